// Round 10
// baseline (93.244 us; speedup 1.0000x reference)
//
#include <hip/hip_runtime.h>
#include <math.h>

#define HD   1024
#define LSEQ 512
#define NB   16
#define KTOP 5
#define NEGV 1e30f

typedef __bf16 bf16x8 __attribute__((ext_vector_type(8)));
typedef float  f32x4  __attribute__((ext_vector_type(4)));

__device__ inline unsigned short f2bf(float f) {
  unsigned u = __float_as_uint(f);
  unsigned r = (u + 0x7FFFu + ((u >> 16) & 1u)) >> 16;
  return (unsigned short)r;
}
__device__ inline float bf2f(unsigned short u) {
  return __uint_as_float(((unsigned)u) << 16);
}

__device__ inline float fast_tanh(float x) {
  float e = __expf(-2.f * fabsf(x));
  float v = (1.f - e) / (1.f + e);
  return copysignf(v, x);
}

// tanh(arg) with pre-scaled xs = A*arg, A = 2*log2(e): tanh = 1 - 2*rcp(1+exp2(xs))
__device__ inline float tanh_scaled(float xs) {
  float e = __builtin_amdgcn_exp2f(xs);
  float r = __builtin_amdgcn_rcpf(1.f + e);
  return fmaf(-2.f, r, 1.f);
}

#define GLDS(g, l) __builtin_amdgcn_global_load_lds(                      \
    (const __attribute__((address_space(1))) unsigned int*)(g),          \
    (__attribute__((address_space(3))) unsigned int*)(l), 16, 0, 0)

// =============== device bodies (scratch passed in; no per-branch __shared__ summing) ===============

// ---- row log_softmax + top5 over 512 (256 threads); sc: >=12 floats ----
__device__ __forceinline__ void sm_body(float* sc, int row, const float* __restrict__ xin,
                                        float* __restrict__ lsm_out,
                                        float* __restrict__ top_out,
                                        float* __restrict__ p_out,
                                        int* __restrict__ idx_out) {
  float* redf = sc;            // [4]
  int* redi = (int*)(sc + 4);  // [4]
  float* bc = sc + 8;          // bc[0]=m, bc[1]=s
  int* bci = (int*)(sc + 10);
  int t = threadIdx.x, lane = t & 63, wid = t >> 6;
  const float* x = xin + (size_t)row * LSEQ;
  float x0 = x[t], x1 = x[t + 256];

  float m = fmaxf(x0, x1);
#pragma unroll
  for (int off = 32; off; off >>= 1) m = fmaxf(m, __shfl_xor(m, off));
  if (lane == 0) redf[wid] = m;
  __syncthreads();
  if (t == 0) bc[0] = fmaxf(fmaxf(redf[0], redf[1]), fmaxf(redf[2], redf[3]));
  __syncthreads();
  m = bc[0];

  float e0 = expf(x0 - m), e1 = expf(x1 - m);
  float s = e0 + e1;
#pragma unroll
  for (int off = 32; off; off >>= 1) s += __shfl_xor(s, off);
  if (lane == 0) redf[wid] = s;
  __syncthreads();
  if (t == 0) bc[1] = redf[0] + redf[1] + redf[2] + redf[3];
  __syncthreads();
  s = bc[1];
  float ls = logf(s);

  lsm_out[(size_t)row * LSEQ + t] = x0 - m - ls;
  lsm_out[(size_t)row * LSEQ + t + 256] = x1 - m - ls;
  if (p_out) {
    float inv = 1.f / s;
    p_out[(size_t)row * LSEQ + t] = e0 * inv;
    p_out[(size_t)row * LSEQ + t + 256] = e1 * inv;
  }

  bool a0 = true, a1 = true;
  for (int it = 0; it < KTOP; ++it) {
    float v0 = a0 ? x0 : -INFINITY;
    float v1 = a1 ? x1 : -INFINITY;
    float bv = v0; int bi = t;
    if (v1 > bv) { bv = v1; bi = t + 256; }
#pragma unroll
    for (int off = 32; off; off >>= 1) {
      float ov = __shfl_xor(bv, off);
      int oi = __shfl_xor(bi, off);
      if (ov > bv || (ov == bv && oi < bi)) { bv = ov; bi = oi; }
    }
    __syncthreads();
    if (lane == 0) { redf[wid] = bv; redi[wid] = bi; }
    __syncthreads();
    if (t == 0) {
      float wv = redf[0]; int wi = redi[0];
      for (int w = 1; w < 4; ++w)
        if (redf[w] > wv || (redf[w] == wv && redi[w] < wi)) { wv = redf[w]; wi = redi[w]; }
      top_out[row * KTOP + it] = wv - m - ls;
      if (idx_out) idx_out[row * KTOP + it] = wi;
      bci[0] = wi;
    }
    __syncthreads();
    int wi = bci[0];
    if (wi == t) a0 = false;
    if (wi == t + 256) a1 = false;
  }
}

// ---- 128x128 MFMA GEMM tile, single-buffered BK=64 (SH: 16384 shorts = 32KB) ----
__device__ __forceinline__ void gemm_body(unsigned short* SH, int R0, int C0,
                                          const unsigned short* __restrict__ Abf,
                                          const unsigned short* __restrict__ Bt,
                                          unsigned short* __restrict__ X1) {
  unsigned short* As = SH;
  unsigned short* Bs = SH + 8192;
  int t = threadIdx.x;
  int w = t >> 6, lane = t & 63, ln = lane & 15, hi = lane >> 4;
  int wr = w >> 1, wc = w & 1;

  f32x4 acc[4][4] = {};

#define STAGE(kc)                                                             \
  do {                                                                        \
    _Pragma("unroll")                                                         \
    for (int p_ = 0; p_ < 4; ++p_) {                                          \
      int rr_ = p_ * 32 + (t >> 3);                                           \
      int cc_ = (t & 7) ^ (rr_ & 7);                                          \
      GLDS(Abf + (size_t)(R0 + rr_) * HD + (kc) + cc_ * 8,                    \
           As + p_ * 2048 + w * 512);                                         \
      GLDS(Bt + (size_t)(C0 + rr_) * HD + (kc) + cc_ * 8,                     \
           Bs + p_ * 2048 + w * 512);                                         \
    }                                                                         \
  } while (0)

  for (int it = 0; it < 16; ++it) {
    if (it) __syncthreads();               // all waves done reading LDS
    STAGE(it * 64);
    asm volatile("s_waitcnt vmcnt(0)" ::: "memory");
    __builtin_amdgcn_s_barrier();
#pragma unroll
    for (int ks = 0; ks < 2; ++ks) {
      bf16x8 av[4], bv[4];
#pragma unroll
      for (int m = 0; m < 4; ++m) {
        int r = wr * 64 + m * 16 + ln;
        av[m] = *(const bf16x8*)(const void*)&As[r * 64 + (((ks * 4 + hi) ^ (r & 7)) * 8)];
      }
#pragma unroll
      for (int n = 0; n < 4; ++n) {
        int r = wc * 64 + n * 16 + ln;
        bv[n] = *(const bf16x8*)(const void*)&Bs[r * 64 + (((ks * 4 + hi) ^ (r & 7)) * 8)];
      }
#pragma unroll
      for (int m = 0; m < 4; ++m)
#pragma unroll
        for (int n = 0; n < 4; ++n)
          acc[m][n] = __builtin_amdgcn_mfma_f32_16x16x32_bf16(av[m], bv[n], acc[m][n], 0, 0, 0);
    }
  }
#undef STAGE

#pragma unroll
  for (int m = 0; m < 4; ++m)
#pragma unroll
    for (int j = 0; j < 4; ++j) {
      int row = R0 + wr * 64 + m * 16 + hi * 4 + j;
#pragma unroll
      for (int n = 0; n < 4; ++n) {
        int col = C0 + wc * 64 + n * 16 + ln;
        X1[(size_t)row * HD + col] = f2bf(acc[m][n][j]);
      }
    }
}

// ---- X2 MFMA gather-GEMM, single-buffered (SH2: 16384 shorts) ----
__device__ __forceinline__ void x2gemm_body(unsigned short* SH2, int cid,
                                            const unsigned short* __restrict__ seqb,
                                            const unsigned short* __restrict__ w2t,
                                            const int* __restrict__ idx,
                                            const float* __restrict__ bei,
                                            float* __restrict__ x2p) {
  unsigned short* As = SH2;
  unsigned short* Bs = SH2 + 8192;
  int t = threadIdx.x;
  int w = t >> 6, lane = t & 63, ln = lane & 15, hi = lane >> 4;
  int wr = w >> 1, wc = w & 1;
  int C0 = cid * 128;

  size_t abase[4];
#pragma unroll
  for (int p_ = 0; p_ < 4; ++p_) {
    int rr = p_ * 32 + (t >> 3);
    int bk = rr < 80 ? rr : 0;
    int l = idx[bk];
    abase[p_] = ((size_t)((bk / KTOP) * LSEQ + l)) * HD;
  }

  f32x4 acc[4][4] = {};

#define STAGE2(kc)                                                            \
  do {                                                                        \
    _Pragma("unroll")                                                         \
    for (int p_ = 0; p_ < 4; ++p_) {                                          \
      int rr_ = p_ * 32 + (t >> 3);                                           \
      int cc_ = (t & 7) ^ (rr_ & 7);                                          \
      GLDS(seqb + abase[p_] + (kc) + cc_ * 8,                                 \
           As + p_ * 2048 + w * 512);                                         \
      GLDS(w2t + (size_t)(C0 + rr_) * HD + (kc) + cc_ * 8,                    \
           Bs + p_ * 2048 + w * 512);                                         \
    }                                                                         \
  } while (0)

  for (int it = 0; it < 16; ++it) {
    if (it) __syncthreads();
    STAGE2(it * 64);
    asm volatile("s_waitcnt vmcnt(0)" ::: "memory");
    __builtin_amdgcn_s_barrier();
#pragma unroll
    for (int ks = 0; ks < 2; ++ks) {
      bf16x8 av[4], bv[4];
#pragma unroll
      for (int m = 0; m < 4; ++m) {
        int r = wr * 64 + m * 16 + ln;
        av[m] = *(const bf16x8*)(const void*)&As[r * 64 + (((ks * 4 + hi) ^ (r & 7)) * 8)];
      }
#pragma unroll
      for (int n = 0; n < 4; ++n) {
        int r = wc * 64 + n * 16 + ln;
        bv[n] = *(const bf16x8*)(const void*)&Bs[r * 64 + (((ks * 4 + hi) ^ (r & 7)) * 8)];
      }
#pragma unroll
      for (int m = 0; m < 4; ++m)
#pragma unroll
        for (int n = 0; n < 4; ++n)
          acc[m][n] = __builtin_amdgcn_mfma_f32_16x16x32_bf16(av[m], bv[n], acc[m][n], 0, 0, 0);
    }
  }
#undef STAGE2

#pragma unroll
  for (int m = 0; m < 4; ++m)
#pragma unroll
    for (int j = 0; j < 4; ++j) {
      int row = wr * 64 + m * 16 + hi * 4 + j;
      if (row < 80) {
#pragma unroll
        for (int n = 0; n < 4; ++n) {
          int col = C0 + wc * 64 + n * 16 + ln;
          x2p[(size_t)row * HD + col] = acc[m][n][j] + bei[col];
        }
      }
    }
}

// ---- answer-feature partial, self-computed softmax, bf16 seq (sc: >=22 floats) ----
__device__ __forceinline__ void ansin_ms_body(float* sc, int q,
                                              const unsigned short* __restrict__ seqb,
                                              const float* __restrict__ seq,
                                              const float* __restrict__ msl,
                                              const int* __restrict__ cls,
                                              float* __restrict__ pa,
                                              float* __restrict__ cf) {
  float* ared = sc;      // [4]
  float* abc = sc + 4;   // abc[0]=m, abc[1]=s
  float* ps = sc + 6;    // [16]
  int b = q >> 5, sl = q & 31, t = threadIdx.x;
  int lane = t & 63, wid = t >> 6;

  const float* x = msl + (size_t)b * LSEQ;
  float x0 = x[t], x1 = x[t + 256];
  float m = fmaxf(x0, x1);
#pragma unroll
  for (int off = 32; off; off >>= 1) m = fmaxf(m, __shfl_xor(m, off));
  if (lane == 0) ared[wid] = m;
  __syncthreads();
  if (t == 0) abc[0] = fmaxf(fmaxf(ared[0], ared[1]), fmaxf(ared[2], ared[3]));
  __syncthreads();
  m = abc[0];
  float e = expf(x0 - m) + expf(x1 - m);
#pragma unroll
  for (int off = 32; off; off >>= 1) e += __shfl_xor(e, off);
  if (lane == 0) ared[wid] = e;
  __syncthreads();
  if (t == 0) abc[1] = ared[0] + ared[1] + ared[2] + ared[3];
  __syncthreads();
  float inv = 1.f / abc[1];
  if (t < 16) ps[t] = expf(x[sl * 16 + t] - m) * inv;
  __syncthreads();

  const unsigned short* sb = seqb + (size_t)(b * LSEQ + sl * 16) * HD;
  float4 acc = make_float4(0.f, 0.f, 0.f, 0.f);
#pragma unroll
  for (int r = 0; r < 16; ++r) {
    ushort4 u = *(const ushort4*)(sb + (size_t)r * HD + 4 * t);
    float p = ps[r];
    acc.x = fmaf(p, bf2f(u.x), acc.x);
    acc.y = fmaf(p, bf2f(u.y), acc.y);
    acc.z = fmaf(p, bf2f(u.z), acc.z);
    acc.w = fmaf(p, bf2f(u.w), acc.w);
  }
  *(float4*)(pa + ((size_t)b * 32 + sl) * HD + 4 * t) = acc;
  if (sl == 0) {
    int ci = cls[b];
    *(float4*)(cf + (size_t)b * HD + 4 * t) =
        *(const float4*)(seq + (size_t)(b * LSEQ + ci) * HD + 4 * t);
  }
}

// ---- answer-feature partial (fallback tier, p_ws based, f32 seq) ----
__device__ __forceinline__ void ansin_body(int q, const float* __restrict__ seq,
                                           const float* __restrict__ p_ws,
                                           const int* __restrict__ cls,
                                           float* __restrict__ pa,
                                           float* __restrict__ cf) {
  __shared__ float ps[16];
  int b = q >> 5, s = q & 31, t = threadIdx.x;
  if (t < 16) ps[t] = p_ws[b * LSEQ + s * 16 + t];
  __syncthreads();
  const float* sb = seq + (size_t)(b * LSEQ + s * 16) * HD;
  float4 acc = make_float4(0.f, 0.f, 0.f, 0.f);
#pragma unroll
  for (int r = 0; r < 16; ++r) {
    float4 v = *(const float4*)(sb + (size_t)r * HD + 4 * t);
    float p = ps[r];
    acc.x = fmaf(p, v.x, acc.x);
    acc.y = fmaf(p, v.y, acc.y);
    acc.z = fmaf(p, v.z, acc.z);
    acc.w = fmaf(p, v.w, acc.w);
  }
  *(float4*)(pa + ((size_t)b * 32 + s) * HD + 4 * t) = acc;
  if (s == 0) {
    int ci = cls[b];
    *(float4*)(cf + (size_t)b * HD + 4 * t) =
        *(const float4*)(seq + (size_t)(b * LSEQ + ci) * HD + 4 * t);
  }
}

// ---- per-row tanh+LN+logit (proven round-5; own LDS, endrow-only kernel) ----
__device__ __forceinline__ void endrow_body(int bx, const unsigned short* __restrict__ X1,
                                            const float* __restrict__ x2p,
                                            const float* __restrict__ gw_ws,
                                            const float* __restrict__ sgb_ws,
                                            const float* __restrict__ mask,
                                            float* __restrict__ mel) {
  __shared__ float x2s[KTOP * HD];  // 20KB, prescaled by A
  const float A = 2.885390081777927f;  // 2*log2(e)
  int t = threadIdx.x, wave = t >> 6, lane = t & 63;
  int row = bx * 4 + wave;
  int b = row >> 9, l = row & 511;

  {
    const float4* src = (const float4*)(x2p + (size_t)b * KTOP * HD);
    float4* dst = (float4*)x2s;
    for (int i = t; i < KTOP * HD / 4; i += 256) {
      float4 v = src[i];
      dst[i] = make_float4(v.x * A, v.y * A, v.z * A, v.w * A);
    }
  }

  float xs[16], gwr[16];
  const unsigned short* xrow = X1 + (size_t)row * HD + lane * 4;
#pragma unroll
  for (int q = 0; q < 4; ++q) {
    ushort4 u = *(const ushort4*)(xrow + q * 256);
    xs[4 * q + 0] = bf2f(u.x) * A;
    xs[4 * q + 1] = bf2f(u.y) * A;
    xs[4 * q + 2] = bf2f(u.z) * A;
    xs[4 * q + 3] = bf2f(u.w) * A;
    float4 g = *(const float4*)(gw_ws + q * 256 + lane * 4);
    gwr[4 * q + 0] = g.x; gwr[4 * q + 1] = g.y;
    gwr[4 * q + 2] = g.z; gwr[4 * q + 3] = g.w;
  }
  float mv = mask[row];
  float sG = sgb_ws[0], sBW = sgb_ws[1];
  __syncthreads();

#pragma unroll
  for (int k = 0; k < KTOP; ++k) {
    float sv = 0.f, s2 = 0.f, sg = 0.f;
#pragma unroll
    for (int q = 0; q < 4; ++q) {
      float4 xq = *(const float4*)&x2s[k * HD + q * 256 + lane * 4];
      float v0 = tanh_scaled(xs[4 * q + 0] + xq.x);
      float v1 = tanh_scaled(xs[4 * q + 1] + xq.y);
      float v2 = tanh_scaled(xs[4 * q + 2] + xq.z);
      float v3 = tanh_scaled(xs[4 * q + 3] + xq.w);
      sv += v0 + v1 + v2 + v3;
      s2 = fmaf(v0, v0, s2); s2 = fmaf(v1, v1, s2);
      s2 = fmaf(v2, v2, s2); s2 = fmaf(v3, v3, s2);
      sg = fmaf(v0, gwr[4 * q + 0], sg); sg = fmaf(v1, gwr[4 * q + 1], sg);
      sg = fmaf(v2, gwr[4 * q + 2], sg); sg = fmaf(v3, gwr[4 * q + 3], sg);
    }
#pragma unroll
    for (int off = 32; off; off >>= 1) {
      sv += __shfl_xor(sv, off);
      s2 += __shfl_xor(s2, off);
      sg += __shfl_xor(sg, off);
    }
    if (lane == 0) {
      float mu = sv * (1.f / (float)HD);
      float var = s2 * (1.f / (float)HD) - mu * mu;
      float rr = rsqrtf(var + 1e-12f);
      float logit = rr * (sg - mu * sG) + sBW;
      mel[((size_t)b * KTOP + k) * LSEQ + l] = logit * mv - NEGV * (1.f - mv);
    }
  }
}

// ---- answer mid GEMM slice (a_s: >=128 floats scratch) ----
__device__ __forceinline__ void ansmid_body(float* a_s, int q, const float* __restrict__ pa,
                                            const float* __restrict__ cf,
                                            const float* __restrict__ Wai,
                                            float* __restrict__ pans) {
  int b = q >> 4, c = q & 15, t = threadIdx.x;
  if (t < 128) {
    int i = c * 128 + t;
    float av;
    if (i < HD) {
      av = 0.f;
#pragma unroll
      for (int s = 0; s < 32; ++s) av += pa[((size_t)b * 32 + s) * HD + i];
    } else {
      av = cf[(size_t)b * HD + (i - HD)];
    }
    a_s[t] = av;
  }
  __syncthreads();
  float4 acc = make_float4(0.f, 0.f, 0.f, 0.f);
#pragma unroll 8
  for (int r = 0; r < 128; ++r) {
    float4 wv = *(const float4*)(Wai + (size_t)(c * 128 + r) * HD + 4 * t);
    float a = a_s[r];
    acc.x = fmaf(a, wv.x, acc.x);
    acc.y = fmaf(a, wv.y, acc.y);
    acc.z = fmaf(a, wv.z, acc.z);
    acc.w = fmaf(a, wv.w, acc.w);
  }
  *(float4*)(pans + ((size_t)b * 16 + c) * HD + 4 * t) = acc;
}

__device__ __forceinline__ void ansfinal_body(float* red, int b, const float* __restrict__ pans,
                                              const float* __restrict__ bai,
                                              const float* __restrict__ Wao,
                                              float* __restrict__ out6) {
  int t = threadIdx.x, lane = t & 63, wid = t >> 6;
  float4 a = *(const float4*)(bai + 4 * t);
#pragma unroll
  for (int c = 0; c < 16; ++c) {
    float4 p = *(const float4*)(pans + ((size_t)b * 16 + c) * HD + 4 * t);
    a.x += p.x; a.y += p.y; a.z += p.z; a.w += p.w;
  }
  float4 wo = *(const float4*)(Wao + 4 * t);
  float part = fast_tanh(a.x) * wo.x + fast_tanh(a.y) * wo.y +
               fast_tanh(a.z) * wo.z + fast_tanh(a.w) * wo.w;
#pragma unroll
  for (int off = 32; off; off >>= 1) part += __shfl_xor(part, off);
  if (lane == 0) red[wid] = part;
  __syncthreads();
  if (t == 0) out6[b] = red[0] + red[1] + red[2] + red[3];
}

// =============== kernels ===============

// K1: conv+start (2048) | W1/W2 transpose (2048) | LN consts (1)
__global__ void k_prep(const float* __restrict__ seq,
                       unsigned short* __restrict__ seqb,
                       const float* __restrict__ Wst,
                       const float* __restrict__ bst,
                       const float* __restrict__ mask,
                       float* __restrict__ msl,
                       const float* __restrict__ Wei,
                       unsigned short* __restrict__ w1t,
                       unsigned short* __restrict__ w2t,
                       const float* __restrict__ gam,
                       const float* __restrict__ bet,
                       const float* __restrict__ Weo,
                       const float* __restrict__ beo,
                       float* __restrict__ gw_ws,
                       float* __restrict__ sgb_ws) {
  __shared__ unsigned short tile[32][33];
  __shared__ float redp[4][2];
  int bx = blockIdx.x;
  if (bx < 2048) {
    int wave = threadIdx.x >> 6, lane = threadIdx.x & 63;
    int row = bx * 4 + wave;
    const float4* s4 = (const float4*)(seq + (size_t)row * HD);
    const float4* w4 = (const float4*)Wst;
    ushort4* o4 = (ushort4*)(seqb + (size_t)row * HD);
    float acc = 0.f;
#pragma unroll
    for (int m = 0; m < 4; ++m) {
      int i = lane + 64 * m;
      float4 a = s4[i], w = w4[i];
      acc += a.x * w.x + a.y * w.y + a.z * w.z + a.w * w.w;
      ushort4 o;
      o.x = f2bf(a.x); o.y = f2bf(a.y); o.z = f2bf(a.z); o.w = f2bf(a.w);
      o4[i] = o;
    }
#pragma unroll
    for (int off = 32; off; off >>= 1) acc += __shfl_xor(acc, off);
    if (lane == 0) {
      float logit = acc + bst[0];
      float mv = mask[row];
      msl[row] = logit * mv - NEGV * (1.f - mv);
    }
  } else if (bx < 4096) {
    int tb = bx - 2048;  // 0..2047: 0..1023 -> W1, 1024..2047 -> W2
    const float* Wsrc = Wei + (tb >= 1024 ? (size_t)HD * HD : 0);
    unsigned short* Wdst = (tb >= 1024) ? w2t : w1t;
    int tb2 = tb & 1023;
    int h0 = (tb2 & 31) * 32, d0 = (tb2 >> 5) * 32;
    int tx = threadIdx.x & 31, ty = threadIdx.x >> 5;
#pragma unroll
    for (int i = 0; i < 4; ++i)
      tile[ty + 8 * i][tx] = f2bf(Wsrc[(size_t)(h0 + ty + 8 * i) * HD + d0 + tx]);
    __syncthreads();
#pragma unroll
    for (int i = 0; i < 4; ++i)
      Wdst[(size_t)(d0 + ty + 8 * i) * HD + h0 + tx] = tile[tx][ty + 8 * i];
  } else {
    int t = threadIdx.x, wave = t >> 6, lane = t & 63;
    float4 g = ((const float4*)gam)[t];
    float4 w = ((const float4*)Weo)[t];
    float4 bv = ((const float4*)bet)[t];
    float4 gwv = make_float4(g.x * w.x, g.y * w.y, g.z * w.z, g.w * w.w);
    ((float4*)gw_ws)[t] = gwv;
    float pg = gwv.x + gwv.y + gwv.z + gwv.w;
    float pb = bv.x * w.x + bv.y * w.y + bv.z * w.z + bv.w * w.w;
#pragma unroll
    for (int off = 32; off; off >>= 1) {
      pg += __shfl_xor(pg, off);
      pb += __shfl_xor(pb, off);
    }
    if (lane == 0) { redp[wave][0] = pg; redp[wave][1] = pb; }
    __syncthreads();
    if (t == 0) {
      sgb_ws[0] = redp[0][0] + redp[1][0] + redp[2][0] + redp[3][0];
      sgb_ws[1] = redp[0][1] + redp[1][1] + redp[2][1] + redp[3][1] + beo[0];
    }
  }
}

__global__ void k_softmax_topk(const float* __restrict__ xin,
                               float* __restrict__ lsm_out,
                               float* __restrict__ top_out,
                               float* __restrict__ p_out,
                               int* __restrict__ idx_out) {
  __shared__ float sc[32];
  sm_body(sc, blockIdx.x, xin, lsm_out, top_out, p_out, idx_out);
}

// K2: merged gemm(512, XCD-affine) + sm1(16) + ansin(512); ONE shared 32KB buffer
__launch_bounds__(256, 4)
__global__ void k_gsm(const unsigned short* __restrict__ Abf,
                      const unsigned short* __restrict__ Bt,
                      unsigned short* __restrict__ X1,
                      const float* __restrict__ msl,
                      float* __restrict__ lsm_out,
                      float* __restrict__ top_out,
                      int* __restrict__ idx_out,
                      const unsigned short* __restrict__ seqb,
                      const float* __restrict__ seq,
                      const int* __restrict__ cls,
                      float* __restrict__ pa,
                      float* __restrict__ cf) {
  __shared__ unsigned short SH[16384];  // 32KB, shared by ALL branches
  int id = blockIdx.x;
  int grp = id >> 4, j = id & 15;
  if (j < 8) {
    int g = grp * 8 + j;                 // g%8 == id%8 -> row-panel XCD affinity
    if (g < 512) gemm_body(SH, (g & 63) * 128, (g >> 6) * 128, Abf, Bt, X1);
  } else {
    int o = grp * 8 + (j - 8);
    if (o < 16) sm_body((float*)SH, o, msl, lsm_out, top_out, nullptr, idx_out);
    else if (o < 528) ansin_ms_body((float*)SH, o - 16, seqb, seq, msl, cls, pa, cf);
  }
}

// K3: x2 gather-gemm (8) + ans_mid (256); shared 32KB buffer
__launch_bounds__(256, 4)
__global__ void k_x2g(const unsigned short* __restrict__ seqb,
                      const unsigned short* __restrict__ w2t,
                      const int* __restrict__ idx,
                      const float* __restrict__ bei,
                      float* __restrict__ x2p,
                      const float* __restrict__ pa,
                      const float* __restrict__ cf,
                      const float* __restrict__ Wai,
                      float* __restrict__ pans) {
  __shared__ unsigned short SH2[16384];
  int id = blockIdx.x;
  if (id < 8) x2gemm_body(SH2, id, seqb, w2t, idx, bei, x2p);
  else ansmid_body((float*)SH2, id - 8, pa, cf, Wai, pans);
}

// K4: endrow (2048)
__global__ void k_end2(const unsigned short* __restrict__ X1,
                       const float* __restrict__ x2p,
                       const float* __restrict__ gw_ws,
                       const float* __restrict__ sgb_ws,
                       const float* __restrict__ mask,
                       float* __restrict__ mel) {
  endrow_body(blockIdx.x, X1, x2p, gw_ws, sgb_ws, mask, mel);
}

// K5: softmax2 (80) + ans_final (16)
__global__ void k_fin(const float* __restrict__ mel,
                      float* __restrict__ lsm_out,
                      float* __restrict__ top_out,
                      const float* __restrict__ pans,
                      const float* __restrict__ bai,
                      const float* __restrict__ Wao,
                      float* __restrict__ out6) {
  __shared__ float sc[32];
  int bx = blockIdx.x;
  if (bx < NB * KTOP) sm_body(sc, bx, mel, lsm_out, top_out, nullptr, nullptr);
  else ansfinal_body(sc, bx - NB * KTOP, pans, bai, Wao, out6);
}

// =============== fallback-tier kernels (small ws) ===============
__global__ void k_x2init(const float* __restrict__ bei, float* __restrict__ x2p) {
  ((float4*)(x2p + (size_t)blockIdx.x * HD))[threadIdx.x] = ((const float4*)bei)[threadIdx.x];
}

__global__ void k_x2f(const float* __restrict__ seq, const int* __restrict__ idx,
                      const float* __restrict__ Wei, float* __restrict__ x2p) {
  __shared__ float srow[128];
  int q = blockIdx.x;
  int bk = q >> 3, s = q & 7, t = threadIdx.x;
  int b = bk / KTOP;
  int l = idx[bk];
  if (t < 128) srow[t] = seq[((size_t)(b * LSEQ + l)) * HD + s * 128 + t];
  __syncthreads();
  const float* W2 = Wei + (size_t)HD * HD + (size_t)s * 128 * HD;
  float4 acc = make_float4(0.f, 0.f, 0.f, 0.f);
#pragma unroll 8
  for (int h = 0; h < 128; ++h) {
    float4 wv = *(const float4*)(W2 + (size_t)h * HD + 4 * t);
    float sv = srow[h];
    acc.x = fmaf(sv, wv.x, acc.x);
    acc.y = fmaf(sv, wv.y, acc.y);
    acc.z = fmaf(sv, wv.z, acc.z);
    acc.w = fmaf(sv, wv.w, acc.w);
  }
  float* dst = x2p + (size_t)bk * HD + 4 * t;
  atomicAdd(dst + 0, acc.x);
  atomicAdd(dst + 1, acc.y);
  atomicAdd(dst + 2, acc.z);
  atomicAdd(dst + 3, acc.w);
}

__global__ void k_ansin_f(const float* __restrict__ seq, const float* __restrict__ p_ws,
                          const int* __restrict__ cls, float* __restrict__ pa,
                          float* __restrict__ cf) {
  ansin_body(blockIdx.x, seq, p_ws, cls, pa, cf);
}
__global__ void k_ansmid_f(const float* __restrict__ pa, const float* __restrict__ cf,
                           const float* __restrict__ Wai, float* __restrict__ pans) {
  __shared__ float a_s[128];
  ansmid_body(a_s, blockIdx.x, pa, cf, Wai, pans);
}

__launch_bounds__(256, 2)
__global__ void k_gemm_end_at(const unsigned short* __restrict__ Abf,
                              const unsigned short* __restrict__ Bt,
                              const float* __restrict__ x2p,
                              const float* __restrict__ gamma,
                              const float* __restrict__ Wout,
                              float* __restrict__ outp) {
  __shared__ unsigned short As[2][128 * 64];
  __shared__ unsigned short Bs[2][128 * 64];
  int t = threadIdx.x;
  int w = t >> 6, lane = t & 63, ln = lane & 15, hi = lane >> 4;
  int wr = w >> 1, wc = w & 1;
  int R0 = blockIdx.x * 128, C0 = blockIdx.y * 128;
  int b = R0 >> 9;
  f32x4 acc[4][4] = {};
#define STAGE(buf, kc)                                                        \
  do {                                                                        \
    _Pragma("unroll")                                                         \
    for (int p_ = 0; p_ < 4; ++p_) {                                          \
      int rr_ = p_ * 32 + (t >> 3);                                           \
      int cc_ = (t & 7) ^ (rr_ & 7);                                          \
      GLDS(Abf + (size_t)(R0 + rr_) * HD + (kc) + cc_ * 8,                    \
           &As[buf][p_ * 2048 + w * 512]);                                    \
      GLDS(Bt + (size_t)(C0 + rr_) * HD + (kc) + cc_ * 8,                     \
           &Bs[buf][p_ * 2048 + w * 512]);                                    \
    }                                                                         \
  } while (0)
  STAGE(0, 0);
  for (int it = 0; it < 16; ++it) {
    int cur = it & 1;
    if (it < 15) {
      STAGE(cur ^ 1, (it + 1) * 64);
      asm volatile("s_waitcnt vmcnt(8)" ::: "memory");
    } else {
      asm volatile("s_waitcnt vmcnt(0)" ::: "memory");
    }
    __builtin_amdgcn_s_barrier();
    __builtin_amdgcn_sched_barrier(0);
#pragma unroll
    for (int ks = 0; ks < 2; ++ks) {
      bf16x8 av[4], bv[4];
#pragma unroll
      for (int m = 0; m < 4; ++m) {
        int r = wr * 64 + m * 16 + ln;
        av[m] = *(const bf16x8*)(const void*)&As[cur][r * 64 + (((ks * 4 + hi) ^ (r & 7)) * 8)];
      }
#pragma unroll
      for (int n = 0; n < 4; ++n) {
        int r = wc * 64 + n * 16 + ln;
        bv[n] = *(const bf16x8*)(const void*)&Bs[cur][r * 64 + (((ks * 4 + hi) ^ (r & 7)) * 8)];
      }
#pragma unroll
      for (int m = 0; m < 4; ++m)
#pragma unroll
        for (int n = 0; n < 4; ++n)
          acc[m][n] = __builtin_amdgcn_mfma_f32_16x16x32_bf16(av[m], bv[n], acc[m][n], 0, 0, 0);
    }
    __builtin_amdgcn_sched_barrier(0);
    __builtin_amdgcn_s_barrier();
  }
#undef STAGE
  float gsv[4];
  float x2v[4][KTOP];
#pragma unroll
  for (int n = 0; n < 4; ++n) {
    int c = C0 + wc * 64 + n * 16 + ln;
    gsv[n] = gamma[c] * Wout[c];
#pragma unroll
    for (int k = 0; k < KTOP; ++k) x2v[n][k] = x2p[((size_t)b * KTOP + k) * HD + c];
  }
#pragma unroll
  for (int m = 0; m < 4; ++m)
#pragma unroll
    for (int j = 0; j < 4; ++j) {
      int row = R0 + wr * 64 + m * 16 + hi * 4 + j;
#pragma unroll
      for (int k = 0; k < KTOP; ++k) {
        float sv = 0.f, s2 = 0.f, sg = 0.f;
#pragma unroll
        for (int n = 0; n < 4; ++n) {
          float v = fast_tanh(acc[m][n][j] + x2v[n][k]);
          sv += v; s2 += v * v; sg += v * gsv[n];
        }
#pragma unroll
        for (int off = 8; off; off >>= 1) {
          sv += __shfl_xor(sv, off);
          s2 += __shfl_xor(s2, off);
          sg += __shfl_xor(sg, off);
        }
        if (ln == 0) {
          float* p = outp + ((size_t)row * KTOP + k) * 3;
          atomicAdd(p, sv);
          atomicAdd(p + 1, s2);
          atomicAdd(p + 2, sg);
        }
      }
    }
}

__global__ void k_end_final(const float* __restrict__ sums,
                            const float* __restrict__ gamma,
                            const float* __restrict__ beta,
                            const float* __restrict__ Wout,
                            const float* __restrict__ beo,
                            const float* __restrict__ mask,
                            float* __restrict__ mel) {
  int bk = blockIdx.x, b = bk / KTOP, k = bk % KTOP;
  int t = threadIdx.x, lane = t & 63, wid = t >> 6;
  __shared__ float red[4][2];
  float pg = 0.f, pb = 0.f;
  for (int i = t; i < HD; i += 256) {
    float wv = Wout[i];
    pg += gamma[i] * wv;
    pb += beta[i] * wv;
  }
#pragma unroll
  for (int off = 32; off; off >>= 1) {
    pg += __shfl_xor(pg, off);
    pb += __shfl_xor(pb, off);
  }
  if (lane == 0) { red[wid][0] = pg; red[wid][1] = pb; }
  __syncthreads();
  float sG = red[0][0] + red[1][0] + red[2][0] + red[3][0];
  float sBW = red[0][1] + red[1][1] + red[2][1] + red[3][1] + beo[0];
  for (int l = t; l < LSEQ; l += 256) {
    int row = b * LSEQ + l;
    const float* s = sums + ((size_t)row * KTOP + k) * 3;
    float sv = s[0], s2 = s[1], sg = s[2];
    float mu = sv * (1.f / (float)HD);
    float var = s2 * (1.f / (float)HD) - mu * mu;
    float rr = rsqrtf(var + 1e-12f);
    float logit = rr * (sg - mu * sG) + sBW;
    float mv = mask[row];
    mel[((size_t)b * KTOP + k) * LSEQ + l] = logit * mv - NEGV * (1.f - mv);
  }
}

// ---------------- host ----------------
extern "C" void kernel_launch(void* const* d_in, const int* in_sizes, int n_in,
                              void* d_out, int out_size, void* d_ws, size_t ws_size,
                              hipStream_t stream) {
  (void)in_sizes; (void)n_in; (void)out_size;
  const float* seq = (const float*)d_in[0];
  const int*   cls = (const int*)d_in[1];
  const float* mask = (const float*)d_in[2];
  const float* Wst = (const float*)d_in[3];
  const float* bst = (const float*)d_in[4];
  const float* Wei = (const float*)d_in[5];
  const float* bei = (const float*)d_in[6];
  const float* gam = (const float*)d_in[7];
  const float* bet = (const float*)d_in[8];
  const float* Weo = (const float*)d_in[9];
  const float* beo = (const float*)d_in[10];
  const float* Wai = (const float*)d_in[11];
  const float* bai = (const float*)d_in[12];
  const float* Wao = (const float*)d_in[13];

  float* out = (float*)d_out;
  float* out0 = out;             // start_predictions  (16,512)
  float* out1 = out0 + 8192;     // end_predictions    (16,5,512)
  float* out2 = out1 + 40960;    // masked_start_logits(16,512)
  float* out3 = out2 + 8192;     // masked_end_logits  (16,5,512)
  float* out4 = out3 + 40960;    // start_top_predictions (16,5)
  float* out5 = out4 + 80;       // end_top_predictions (16,25)
  float* out6 = out5 + 400;      // class_logits (16)

  // ws layout
  char* p = (char*)d_ws;
  unsigned short* seqb = (unsigned short*)p;  p += (size_t)8192 * 1024 * 2;
  unsigned short* w1t  = (unsigned short*)p;  p += (size_t)1024 * 1024 * 2;
  unsigned short* w2t  = (unsigned short*)p;  p += (size_t)1024 * 1024 * 2;
  float* p_ws   = (float*)p;                  p += 8192 * 4;
  int*   idx_ws = (int*)p;                    p += 128 * 4;
  float* x2p    = (float*)p;                  p += (size_t)80 * 1024 * 4;
  float* gw_ws  = (float*)p;                  p += 1024 * 4;
  float* sgb_ws = (float*)p;                  p += 4 * 4;
  float* pa     = (float*)p;                  p += (size_t)16 * 32 * 1024 * 4;
  float* cf     = (float*)p;                  p += (size_t)16 * 1024 * 4;
  float* pans   = (float*)p;                  p += (size_t)16 * 16 * 1024 * 4;
  // tail: X1 (big tier, 16MB) or sums (small tier, 480KB)
  unsigned short* x1 = (unsigned short*)p;
  float* sums = (float*)p;
  size_t base = (size_t)(p - (char*)d_ws);
  size_t need_big = base + (size_t)8192 * 1024 * 2;
  size_t need_small = base + (size_t)8192 * KTOP * 3 * 4;

  k_prep<<<4097, 256, 0, stream>>>(seq, seqb, Wst, bst, mask, out2, Wei, w1t, w2t,
                                   gam, bet, Weo, beo, gw_ws, sgb_ws);

  if (ws_size >= need_big) {
    // gemm(512) + sm1(16) + ansin(512, bf16 src, self-softmax) in one launch
    k_gsm<<<1056, 256, 0, stream>>>(seqb, w1t, x1, out2, out0, out4, idx_ws,
                                    seqb, seq, cls, pa, cf);
    k_x2g<<<264, 256, 0, stream>>>(seqb, w2t, idx_ws, bei, x2p, pa, cf, Wai, pans);
    k_end2<<<2048, 256, 0, stream>>>(x1, x2p, gw_ws, sgb_ws, mask, out3);
  } else if (ws_size >= need_small) {
    k_softmax_topk<<<NB, 256, 0, stream>>>(out2, out0, out4, p_ws, idx_ws);
    k_x2init<<<80, 256, 0, stream>>>(bei, x2p);
    k_x2f<<<640, 256, 0, stream>>>(seq, idx_ws, Wei, x2p);
    hipMemsetAsync(sums, 0, (size_t)8192 * KTOP * 3 * sizeof(float), stream);
    k_gemm_end_at<<<dim3(64, 8), 256, 0, stream>>>(seqb, w1t, x2p, gam, Weo, sums);
    k_end_final<<<NB * KTOP, 256, 0, stream>>>(sums, gam, bet, Weo, beo, mask, out3);
    k_ansin_f<<<512, 256, 0, stream>>>(seq, p_ws, cls, pa, cf);
    k_ansmid_f<<<256, 256, 0, stream>>>(pa, cf, Wai, pans);
  }

  k_fin<<<96, 256, 0, stream>>>(out3, out1, out5, pans, bai, Wao, out6);
}

// Round 11
// 86.779 us; speedup vs baseline: 1.0745x; 1.0745x over previous
//
#include <hip/hip_runtime.h>
#include <math.h>

#define HD   1024
#define LSEQ 512
#define NB   16
#define KTOP 5
#define NEGV 1e30f

typedef __bf16 bf16x8 __attribute__((ext_vector_type(8)));
typedef float  f32x4  __attribute__((ext_vector_type(4)));

__device__ inline unsigned short f2bf(float f) {
  unsigned u = __float_as_uint(f);
  unsigned r = (u + 0x7FFFu + ((u >> 16) & 1u)) >> 16;
  return (unsigned short)r;
}
__device__ inline float bf2f(unsigned short u) {
  return __uint_as_float(((unsigned)u) << 16);
}

__device__ inline float fast_tanh(float x) {
  float e = __expf(-2.f * fabsf(x));
  float v = (1.f - e) / (1.f + e);
  return copysignf(v, x);
}

// sum across each 16-lane DPP row via rotate-reduce (VALU pipe, no LDS ops)
__device__ inline float dpp_row_reduce16(float v) {
  int t;
  t = __builtin_amdgcn_update_dpp(0, __float_as_int(v), 0x128, 0xf, 0xf, true);
  v += __int_as_float(t);   // row_ror:8
  t = __builtin_amdgcn_update_dpp(0, __float_as_int(v), 0x124, 0xf, 0xf, true);
  v += __int_as_float(t);   // row_ror:4
  t = __builtin_amdgcn_update_dpp(0, __float_as_int(v), 0x122, 0xf, 0xf, true);
  v += __int_as_float(t);   // row_ror:2
  t = __builtin_amdgcn_update_dpp(0, __float_as_int(v), 0x121, 0xf, 0xf, true);
  v += __int_as_float(t);   // row_ror:1
  return v;
}

#define GLDS(g, l) __builtin_amdgcn_global_load_lds(                      \
    (const __attribute__((address_space(1))) unsigned int*)(g),          \
    (__attribute__((address_space(3))) unsigned int*)(l), 16, 0, 0)

// =============== device bodies ===============

// ---- row log_softmax + top5 over 512 (256 threads) ----
__device__ __forceinline__ void sm_body(int row, const float* __restrict__ xin,
                                        float* __restrict__ lsm_out,
                                        float* __restrict__ top_out,
                                        float* __restrict__ p_out,
                                        int* __restrict__ idx_out) {
  __shared__ float redf[4];
  __shared__ int redi[4];
  __shared__ float bc_m, bc_s;
  __shared__ int bc_i;
  int t = threadIdx.x, lane = t & 63, wid = t >> 6;
  const float* x = xin + (size_t)row * LSEQ;
  float x0 = x[t], x1 = x[t + 256];

  float m = fmaxf(x0, x1);
#pragma unroll
  for (int off = 32; off; off >>= 1) m = fmaxf(m, __shfl_xor(m, off));
  if (lane == 0) redf[wid] = m;
  __syncthreads();
  if (t == 0) bc_m = fmaxf(fmaxf(redf[0], redf[1]), fmaxf(redf[2], redf[3]));
  __syncthreads();
  m = bc_m;

  float e0 = expf(x0 - m), e1 = expf(x1 - m);
  float s = e0 + e1;
#pragma unroll
  for (int off = 32; off; off >>= 1) s += __shfl_xor(s, off);
  if (lane == 0) redf[wid] = s;
  __syncthreads();
  if (t == 0) bc_s = redf[0] + redf[1] + redf[2] + redf[3];
  __syncthreads();
  s = bc_s;
  float ls = logf(s);

  lsm_out[(size_t)row * LSEQ + t] = x0 - m - ls;
  lsm_out[(size_t)row * LSEQ + t + 256] = x1 - m - ls;
  if (p_out) {
    float inv = 1.f / s;
    p_out[(size_t)row * LSEQ + t] = e0 * inv;
    p_out[(size_t)row * LSEQ + t + 256] = e1 * inv;
  }

  bool a0 = true, a1 = true;
  for (int it = 0; it < KTOP; ++it) {
    float v0 = a0 ? x0 : -INFINITY;
    float v1 = a1 ? x1 : -INFINITY;
    float bv = v0; int bi = t;
    if (v1 > bv) { bv = v1; bi = t + 256; }
#pragma unroll
    for (int off = 32; off; off >>= 1) {
      float ov = __shfl_xor(bv, off);
      int oi = __shfl_xor(bi, off);
      if (ov > bv || (ov == bv && oi < bi)) { bv = ov; bi = oi; }
    }
    __syncthreads();
    if (lane == 0) { redf[wid] = bv; redi[wid] = bi; }
    __syncthreads();
    if (t == 0) {
      float wv = redf[0]; int wi = redi[0];
      for (int w = 1; w < 4; ++w)
        if (redf[w] > wv || (redf[w] == wv && redi[w] < wi)) { wv = redf[w]; wi = redi[w]; }
      top_out[row * KTOP + it] = wv - m - ls;
      if (idx_out) idx_out[row * KTOP + it] = wi;
      bc_i = wi;
    }
    __syncthreads();
    int wi = bc_i;
    if (wi == t) a0 = false;
    if (wi == t + 256) a1 = false;
  }
}

// ---- 128x128 MFMA GEMM tile, single-buffered BK=64 (32KB LDS, m97 pattern) ----
__device__ __forceinline__ void gemm_body(int R0, int C0,
                                          const unsigned short* __restrict__ Abf,
                                          const unsigned short* __restrict__ Bt,
                                          unsigned short* __restrict__ X1) {
  __shared__ unsigned short SH[16384];  // As[8192] | Bs[8192]  (32KB)
  unsigned short* As = SH;
  unsigned short* Bs = SH + 8192;
  int t = threadIdx.x;
  int w = t >> 6, lane = t & 63, ln = lane & 15, hi = lane >> 4;
  int wr = w >> 1, wc = w & 1;

  f32x4 acc[4][4] = {};

#define STAGE(kc)                                                             \
  do {                                                                        \
    _Pragma("unroll")                                                         \
    for (int p_ = 0; p_ < 4; ++p_) {                                          \
      int rr_ = p_ * 32 + (t >> 3);                                           \
      int cc_ = (t & 7) ^ (rr_ & 7);                                          \
      GLDS(Abf + (size_t)(R0 + rr_) * HD + (kc) + cc_ * 8,                    \
           As + p_ * 2048 + w * 512);                                         \
      GLDS(Bt + (size_t)(C0 + rr_) * HD + (kc) + cc_ * 8,                     \
           Bs + p_ * 2048 + w * 512);                                         \
    }                                                                         \
  } while (0)

  for (int it = 0; it < 16; ++it) {
    if (it) __syncthreads();               // all waves done reading LDS
    STAGE(it * 64);
    asm volatile("s_waitcnt vmcnt(0)" ::: "memory");
    __builtin_amdgcn_s_barrier();
#pragma unroll
    for (int ks = 0; ks < 2; ++ks) {
      bf16x8 av[4], bv[4];
#pragma unroll
      for (int m = 0; m < 4; ++m) {
        int r = wr * 64 + m * 16 + ln;
        av[m] = *(const bf16x8*)(const void*)&As[r * 64 + (((ks * 4 + hi) ^ (r & 7)) * 8)];
      }
#pragma unroll
      for (int n = 0; n < 4; ++n) {
        int r = wc * 64 + n * 16 + ln;
        bv[n] = *(const bf16x8*)(const void*)&Bs[r * 64 + (((ks * 4 + hi) ^ (r & 7)) * 8)];
      }
#pragma unroll
      for (int m = 0; m < 4; ++m)
#pragma unroll
        for (int n = 0; n < 4; ++n)
          acc[m][n] = __builtin_amdgcn_mfma_f32_16x16x32_bf16(av[m], bv[n], acc[m][n], 0, 0, 0);
    }
  }
#undef STAGE

#pragma unroll
  for (int m = 0; m < 4; ++m)
#pragma unroll
    for (int j = 0; j < 4; ++j) {
      int row = R0 + wr * 64 + m * 16 + hi * 4 + j;
#pragma unroll
      for (int n = 0; n < 4; ++n) {
        int col = C0 + wc * 64 + n * 16 + ln;
        X1[(size_t)row * HD + col] = f2bf(acc[m][n][j]);
      }
    }
}

// ---- X2 MFMA gather-GEMM, single-buffered ----
__device__ __forceinline__ void x2gemm_body(int cid,
                                            const unsigned short* __restrict__ seqb,
                                            const unsigned short* __restrict__ w2t,
                                            const int* __restrict__ idx,
                                            const float* __restrict__ bei,
                                            float* __restrict__ x2p) {
  __shared__ unsigned short SH2[16384];
  unsigned short* As = SH2;
  unsigned short* Bs = SH2 + 8192;
  int t = threadIdx.x;
  int w = t >> 6, lane = t & 63, ln = lane & 15, hi = lane >> 4;
  int wr = w >> 1, wc = w & 1;
  int C0 = cid * 128;

  size_t abase[4];
#pragma unroll
  for (int p_ = 0; p_ < 4; ++p_) {
    int rr = p_ * 32 + (t >> 3);
    int bk = rr < 80 ? rr : 0;
    int l = idx[bk];
    abase[p_] = ((size_t)((bk / KTOP) * LSEQ + l)) * HD;
  }

  f32x4 acc[4][4] = {};

#define STAGE2(kc)                                                            \
  do {                                                                        \
    _Pragma("unroll")                                                         \
    for (int p_ = 0; p_ < 4; ++p_) {                                          \
      int rr_ = p_ * 32 + (t >> 3);                                           \
      int cc_ = (t & 7) ^ (rr_ & 7);                                          \
      GLDS(seqb + abase[p_] + (kc) + cc_ * 8,                                 \
           As + p_ * 2048 + w * 512);                                         \
      GLDS(w2t + (size_t)(C0 + rr_) * HD + (kc) + cc_ * 8,                    \
           Bs + p_ * 2048 + w * 512);                                         \
    }                                                                         \
  } while (0)

  for (int it = 0; it < 16; ++it) {
    if (it) __syncthreads();
    STAGE2(it * 64);
    asm volatile("s_waitcnt vmcnt(0)" ::: "memory");
    __builtin_amdgcn_s_barrier();
#pragma unroll
    for (int ks = 0; ks < 2; ++ks) {
      bf16x8 av[4], bv[4];
#pragma unroll
      for (int m = 0; m < 4; ++m) {
        int r = wr * 64 + m * 16 + ln;
        av[m] = *(const bf16x8*)(const void*)&As[r * 64 + (((ks * 4 + hi) ^ (r & 7)) * 8)];
      }
#pragma unroll
      for (int n = 0; n < 4; ++n) {
        int r = wc * 64 + n * 16 + ln;
        bv[n] = *(const bf16x8*)(const void*)&Bs[r * 64 + (((ks * 4 + hi) ^ (r & 7)) * 8)];
      }
#pragma unroll
      for (int m = 0; m < 4; ++m)
#pragma unroll
        for (int n = 0; n < 4; ++n)
          acc[m][n] = __builtin_amdgcn_mfma_f32_16x16x32_bf16(av[m], bv[n], acc[m][n], 0, 0, 0);
    }
  }
#undef STAGE2

#pragma unroll
  for (int m = 0; m < 4; ++m)
#pragma unroll
    for (int j = 0; j < 4; ++j) {
      int row = wr * 64 + m * 16 + hi * 4 + j;
      if (row < 80) {
#pragma unroll
        for (int n = 0; n < 4; ++n) {
          int col = C0 + wc * 64 + n * 16 + ln;
          x2p[(size_t)row * HD + col] = acc[m][n][j] + bei[col];
        }
      }
    }
}

// ---- answer-feature partial (uses p_ws from sm1) ----
__device__ __forceinline__ void ansin_body(int q, const float* __restrict__ seq,
                                           const float* __restrict__ p_ws,
                                           const int* __restrict__ cls,
                                           float* __restrict__ pa,
                                           float* __restrict__ cf) {
  __shared__ float ps[16];
  int b = q >> 5, s = q & 31, t = threadIdx.x;
  if (t < 16) ps[t] = p_ws[b * LSEQ + s * 16 + t];
  __syncthreads();
  const float* sb = seq + (size_t)(b * LSEQ + s * 16) * HD;
  float4 acc = make_float4(0.f, 0.f, 0.f, 0.f);
#pragma unroll
  for (int r = 0; r < 16; ++r) {
    float4 v = *(const float4*)(sb + (size_t)r * HD + 4 * t);
    float p = ps[r];
    acc.x = fmaf(p, v.x, acc.x);
    acc.y = fmaf(p, v.y, acc.y);
    acc.z = fmaf(p, v.z, acc.z);
    acc.w = fmaf(p, v.w, acc.w);
  }
  *(float4*)(pa + ((size_t)b * 32 + s) * HD + 4 * t) = acc;
  if (s == 0) {
    int ci = cls[b];
    *(float4*)(cf + (size_t)b * HD + 4 * t) =
        *(const float4*)(seq + (size_t)(b * LSEQ + ci) * HD + 4 * t);
  }
}

// ---- per-row tanh+LN+logit: 16 rows/block, 16-lane group per row, DPP reduce ----
// tanh(x1+x2) = 1 - 2*rcp(1 + exp2(A*x1)*exp2(A*x2)), A = 2*log2(e).
// E2 = exp2(A*x2) staged in LDS once per block; E1 computed once per element.
__device__ __forceinline__ void endrow_body(int bx, const unsigned short* __restrict__ X1,
                                            const float* __restrict__ x2p,
                                            const float* __restrict__ gw_ws,
                                            const float* __restrict__ sgb_ws,
                                            const float* __restrict__ mask,
                                            float* __restrict__ mel) {
  __shared__ float x2e[KTOP * HD];  // 20KB: exp2(A*x2)
  const float A = 2.885390081777927f;  // 2*log2(e)
  int t = threadIdx.x, wave = t >> 6, lane = t & 63;
  int g = lane >> 4, l16 = lane & 15;
  int row = bx * 16 + wave * 4 + g;   // 512*16 = 8192 rows; same b per block (512%16==0)
  int b = row >> 9, l = row & 511;

  {
    const float* src = x2p + (size_t)b * KTOP * HD;
    for (int i = t; i < KTOP * HD; i += 256)
      x2e[i] = __builtin_amdgcn_exp2f(src[i] * A);
  }
  float mv = mask[row];
  float sG = sgb_ws[0], sBW = sgb_ws[1];
  __syncthreads();

  float av[KTOP] = {}, a2[KTOP] = {}, ag[KTOP] = {};
  const unsigned short* xrow = X1 + (size_t)row * HD;
#pragma unroll 4
  for (int j = 0; j < 16; ++j) {
    int col = j * 64 + l16 * 4;       // 16 lanes cover 128B contiguous per row
    ushort4 u = *(const ushort4*)(xrow + col);
    float4 gwv = *(const float4*)(gw_ws + col);
    float e0 = __builtin_amdgcn_exp2f(bf2f(u.x) * A);
    float e1 = __builtin_amdgcn_exp2f(bf2f(u.y) * A);
    float e2 = __builtin_amdgcn_exp2f(bf2f(u.z) * A);
    float e3 = __builtin_amdgcn_exp2f(bf2f(u.w) * A);
#pragma unroll
    for (int k = 0; k < KTOP; ++k) {
      float4 xq = *(const float4*)&x2e[k * HD + col];
      float v0 = fmaf(-2.f, __builtin_amdgcn_rcpf(fmaf(e0, xq.x, 1.f)), 1.f);
      float v1 = fmaf(-2.f, __builtin_amdgcn_rcpf(fmaf(e1, xq.y, 1.f)), 1.f);
      float v2 = fmaf(-2.f, __builtin_amdgcn_rcpf(fmaf(e2, xq.z, 1.f)), 1.f);
      float v3 = fmaf(-2.f, __builtin_amdgcn_rcpf(fmaf(e3, xq.w, 1.f)), 1.f);
      av[k] += v0 + v1 + v2 + v3;
      a2[k] = fmaf(v0, v0, a2[k]); a2[k] = fmaf(v1, v1, a2[k]);
      a2[k] = fmaf(v2, v2, a2[k]); a2[k] = fmaf(v3, v3, a2[k]);
      ag[k] = fmaf(v0, gwv.x, ag[k]); ag[k] = fmaf(v1, gwv.y, ag[k]);
      ag[k] = fmaf(v2, gwv.z, ag[k]); ag[k] = fmaf(v3, gwv.w, ag[k]);
    }
  }
#pragma unroll
  for (int k = 0; k < KTOP; ++k) {
    float sv = dpp_row_reduce16(av[k]);
    float s2 = dpp_row_reduce16(a2[k]);
    float sg = dpp_row_reduce16(ag[k]);
    if (l16 == 0) {
      float mu = sv * (1.f / (float)HD);
      float var = s2 * (1.f / (float)HD) - mu * mu;
      float rr = rsqrtf(var + 1e-12f);
      float logit = rr * (sg - mu * sG) + sBW;
      mel[((size_t)b * KTOP + k) * LSEQ + l] = logit * mv - NEGV * (1.f - mv);
    }
  }
}

// ---- answer mid GEMM slice ----
__device__ __forceinline__ void ansmid_body(int q, const float* __restrict__ pa,
                                            const float* __restrict__ cf,
                                            const float* __restrict__ Wai,
                                            float* __restrict__ pans) {
  __shared__ float a_s[128];
  int b = q >> 4, c = q & 15, t = threadIdx.x;
  if (t < 128) {
    int i = c * 128 + t;
    float av;
    if (i < HD) {
      av = 0.f;
#pragma unroll
      for (int s = 0; s < 32; ++s) av += pa[((size_t)b * 32 + s) * HD + i];
    } else {
      av = cf[(size_t)b * HD + (i - HD)];
    }
    a_s[t] = av;
  }
  __syncthreads();
  float4 acc = make_float4(0.f, 0.f, 0.f, 0.f);
#pragma unroll 8
  for (int r = 0; r < 128; ++r) {
    float4 wv = *(const float4*)(Wai + (size_t)(c * 128 + r) * HD + 4 * t);
    float a = a_s[r];
    acc.x = fmaf(a, wv.x, acc.x);
    acc.y = fmaf(a, wv.y, acc.y);
    acc.z = fmaf(a, wv.z, acc.z);
    acc.w = fmaf(a, wv.w, acc.w);
  }
  *(float4*)(pans + ((size_t)b * 16 + c) * HD + 4 * t) = acc;
}

__device__ __forceinline__ void ansfinal_body(int b, const float* __restrict__ pans,
                                              const float* __restrict__ bai,
                                              const float* __restrict__ Wao,
                                              float* __restrict__ out6) {
  __shared__ float red[4];
  int t = threadIdx.x, lane = t & 63, wid = t >> 6;
  float4 a = *(const float4*)(bai + 4 * t);
#pragma unroll
  for (int c = 0; c < 16; ++c) {
    float4 p = *(const float4*)(pans + ((size_t)b * 16 + c) * HD + 4 * t);
    a.x += p.x; a.y += p.y; a.z += p.z; a.w += p.w;
  }
  float4 wo = *(const float4*)(Wao + 4 * t);
  float part = fast_tanh(a.x) * wo.x + fast_tanh(a.y) * wo.y +
               fast_tanh(a.z) * wo.z + fast_tanh(a.w) * wo.w;
#pragma unroll
  for (int off = 32; off; off >>= 1) part += __shfl_xor(part, off);
  if (lane == 0) red[wid] = part;
  __syncthreads();
  if (t == 0) out6[b] = red[0] + red[1] + red[2] + red[3];
}

// =============== kernels ===============

// K1: conv+start (2048) | W1/W2 transpose (2048) | LN consts (1)
__global__ void k_prep(const float* __restrict__ seq,
                       unsigned short* __restrict__ seqb,
                       const float* __restrict__ Wst,
                       const float* __restrict__ bst,
                       const float* __restrict__ mask,
                       float* __restrict__ msl,
                       const float* __restrict__ Wei,
                       unsigned short* __restrict__ w1t,
                       unsigned short* __restrict__ w2t,
                       const float* __restrict__ gam,
                       const float* __restrict__ bet,
                       const float* __restrict__ Weo,
                       const float* __restrict__ beo,
                       float* __restrict__ gw_ws,
                       float* __restrict__ sgb_ws) {
  __shared__ unsigned short tile[32][33];
  __shared__ float redp[4][2];
  int bx = blockIdx.x;
  if (bx < 2048) {
    int wave = threadIdx.x >> 6, lane = threadIdx.x & 63;
    int row = bx * 4 + wave;
    const float4* s4 = (const float4*)(seq + (size_t)row * HD);
    const float4* w4 = (const float4*)Wst;
    ushort4* o4 = (ushort4*)(seqb + (size_t)row * HD);
    float acc = 0.f;
#pragma unroll
    for (int m = 0; m < 4; ++m) {
      int i = lane + 64 * m;
      float4 a = s4[i], w = w4[i];
      acc += a.x * w.x + a.y * w.y + a.z * w.z + a.w * w.w;
      ushort4 o;
      o.x = f2bf(a.x); o.y = f2bf(a.y); o.z = f2bf(a.z); o.w = f2bf(a.w);
      o4[i] = o;
    }
#pragma unroll
    for (int off = 32; off; off >>= 1) acc += __shfl_xor(acc, off);
    if (lane == 0) {
      float logit = acc + bst[0];
      float mv = mask[row];
      msl[row] = logit * mv - NEGV * (1.f - mv);
    }
  } else if (bx < 4096) {
    int tb = bx - 2048;  // 0..2047: 0..1023 -> W1, 1024..2047 -> W2
    const float* Wsrc = Wei + (tb >= 1024 ? (size_t)HD * HD : 0);
    unsigned short* Wdst = (tb >= 1024) ? w2t : w1t;
    int tb2 = tb & 1023;
    int h0 = (tb2 & 31) * 32, d0 = (tb2 >> 5) * 32;
    int tx = threadIdx.x & 31, ty = threadIdx.x >> 5;
#pragma unroll
    for (int i = 0; i < 4; ++i)
      tile[ty + 8 * i][tx] = f2bf(Wsrc[(size_t)(h0 + ty + 8 * i) * HD + d0 + tx]);
    __syncthreads();
#pragma unroll
    for (int i = 0; i < 4; ++i)
      Wdst[(size_t)(d0 + ty + 8 * i) * HD + h0 + tx] = tile[tx][ty + 8 * i];
  } else {
    int t = threadIdx.x, wave = t >> 6, lane = t & 63;
    float4 g = ((const float4*)gam)[t];
    float4 w = ((const float4*)Weo)[t];
    float4 bv = ((const float4*)bet)[t];
    float4 gwv = make_float4(g.x * w.x, g.y * w.y, g.z * w.z, g.w * w.w);
    ((float4*)gw_ws)[t] = gwv;
    float pg = gwv.x + gwv.y + gwv.z + gwv.w;
    float pb = bv.x * w.x + bv.y * w.y + bv.z * w.z + bv.w * w.w;
#pragma unroll
    for (int off = 32; off; off >>= 1) {
      pg += __shfl_xor(pg, off);
      pb += __shfl_xor(pb, off);
    }
    if (lane == 0) { redp[wave][0] = pg; redp[wave][1] = pb; }
    __syncthreads();
    if (t == 0) {
      sgb_ws[0] = redp[0][0] + redp[1][0] + redp[2][0] + redp[3][0];
      sgb_ws[1] = redp[0][1] + redp[1][1] + redp[2][1] + redp[3][1] + beo[0];
    }
  }
}

__global__ void k_softmax_topk(const float* __restrict__ xin,
                               float* __restrict__ lsm_out,
                               float* __restrict__ top_out,
                               float* __restrict__ p_out,
                               int* __restrict__ idx_out) {
  sm_body(blockIdx.x, xin, lsm_out, top_out, p_out, idx_out);
}

// K2: sm1 (ids 0..15) + XCD-affine gemm (ids 16..527)
__launch_bounds__(256, 4)
__global__ void k_gsm(const unsigned short* __restrict__ Abf,
                      const unsigned short* __restrict__ Bt,
                      unsigned short* __restrict__ X1,
                      const float* __restrict__ msl,
                      float* __restrict__ lsm_out,
                      float* __restrict__ top_out,
                      float* __restrict__ p_out,
                      int* __restrict__ idx_out) {
  int id = blockIdx.x;
  if (id < 16) {
    sm_body(id, msl, lsm_out, top_out, p_out, idx_out);
  } else {
    int gid = id - 16;  // gid%8 == id%8 -> row-panel XCD affinity
    gemm_body((gid & 63) * 128, (gid >> 6) * 128, Abf, Bt, X1);
  }
}

// K3: x2 MFMA gather-gemm (ids 0..7) + ans_in (ids 8..519)
__launch_bounds__(256, 4)
__global__ void k_x2a(const unsigned short* __restrict__ seqb,
                      const unsigned short* __restrict__ w2t,
                      const int* __restrict__ idx,
                      const float* __restrict__ bei,
                      float* __restrict__ x2p,
                      const float* __restrict__ seq,
                      const float* __restrict__ p_ws,
                      const int* __restrict__ cls,
                      float* __restrict__ pa,
                      float* __restrict__ cf) {
  int id = blockIdx.x;
  if (id < 8) x2gemm_body(id, seqb, w2t, idx, bei, x2p);
  else ansin_body(id - 8, seq, p_ws, cls, pa, cf);
}

// K4: endrow (512, 16 rows each) + ans_mid (256)
__global__ void k_end2(const unsigned short* __restrict__ X1,
                       const float* __restrict__ x2p,
                       const float* __restrict__ gw_ws,
                       const float* __restrict__ sgb_ws,
                       const float* __restrict__ mask,
                       float* __restrict__ mel,
                       const float* __restrict__ pa,
                       const float* __restrict__ cf,
                       const float* __restrict__ Wai,
                       float* __restrict__ pans) {
  int bx = blockIdx.x;
  if (bx < 512) endrow_body(bx, X1, x2p, gw_ws, sgb_ws, mask, mel);
  else ansmid_body(bx - 512, pa, cf, Wai, pans);
}

// K5: softmax2 (80) + ans_final (16)
__global__ void k_fin(const float* __restrict__ mel,
                      float* __restrict__ lsm_out,
                      float* __restrict__ top_out,
                      const float* __restrict__ pans,
                      const float* __restrict__ bai,
                      const float* __restrict__ Wao,
                      float* __restrict__ out6) {
  int bx = blockIdx.x;
  if (bx < NB * KTOP) sm_body(bx, mel, lsm_out, top_out, nullptr, nullptr);
  else ansfinal_body(bx - NB * KTOP, pans, bai, Wao, out6);
}

// =============== fallback-tier kernels (small ws) ===============
__global__ void k_x2init(const float* __restrict__ bei, float* __restrict__ x2p) {
  ((float4*)(x2p + (size_t)blockIdx.x * HD))[threadIdx.x] = ((const float4*)bei)[threadIdx.x];
}

__global__ void k_x2f(const float* __restrict__ seq, const int* __restrict__ idx,
                      const float* __restrict__ Wei, float* __restrict__ x2p) {
  __shared__ float srow[128];
  int q = blockIdx.x;
  int bk = q >> 3, s = q & 7, t = threadIdx.x;
  int b = bk / KTOP;
  int l = idx[bk];
  if (t < 128) srow[t] = seq[((size_t)(b * LSEQ + l)) * HD + s * 128 + t];
  __syncthreads();
  const float* W2 = Wei + (size_t)HD * HD + (size_t)s * 128 * HD;
  float4 acc = make_float4(0.f, 0.f, 0.f, 0.f);
#pragma unroll 8
  for (int h = 0; h < 128; ++h) {
    float4 wv = *(const float4*)(W2 + (size_t)h * HD + 4 * t);
    float sv = srow[h];
    acc.x = fmaf(sv, wv.x, acc.x);
    acc.y = fmaf(sv, wv.y, acc.y);
    acc.z = fmaf(sv, wv.z, acc.z);
    acc.w = fmaf(sv, wv.w, acc.w);
  }
  float* dst = x2p + (size_t)bk * HD + 4 * t;
  atomicAdd(dst + 0, acc.x);
  atomicAdd(dst + 1, acc.y);
  atomicAdd(dst + 2, acc.z);
  atomicAdd(dst + 3, acc.w);
}

__global__ void k_ansin_f(const float* __restrict__ seq, const float* __restrict__ p_ws,
                          const int* __restrict__ cls, float* __restrict__ pa,
                          float* __restrict__ cf) {
  ansin_body(blockIdx.x, seq, p_ws, cls, pa, cf);
}
__global__ void k_ansmid_f(const float* __restrict__ pa, const float* __restrict__ cf,
                           const float* __restrict__ Wai, float* __restrict__ pans) {
  ansmid_body(blockIdx.x, pa, cf, Wai, pans);
}

__launch_bounds__(256, 2)
__global__ void k_gemm_end_at(const unsigned short* __restrict__ Abf,
                              const unsigned short* __restrict__ Bt,
                              const float* __restrict__ x2p,
                              const float* __restrict__ gamma,
                              const float* __restrict__ Wout,
                              float* __restrict__ outp) {
  __shared__ unsigned short As[2][128 * 64];
  __shared__ unsigned short Bs[2][128 * 64];
  int t = threadIdx.x;
  int w = t >> 6, lane = t & 63, ln = lane & 15, hi = lane >> 4;
  int wr = w >> 1, wc = w & 1;
  int R0 = blockIdx.x * 128, C0 = blockIdx.y * 128;
  int b = R0 >> 9;
  f32x4 acc[4][4] = {};
#define STAGE(buf, kc)                                                        \
  do {                                                                        \
    _Pragma("unroll")                                                         \
    for (int p_ = 0; p_ < 4; ++p_) {                                          \
      int rr_ = p_ * 32 + (t >> 3);                                           \
      int cc_ = (t & 7) ^ (rr_ & 7);                                          \
      GLDS(Abf + (size_t)(R0 + rr_) * HD + (kc) + cc_ * 8,                    \
           &As[buf][p_ * 2048 + w * 512]);                                    \
      GLDS(Bt + (size_t)(C0 + rr_) * HD + (kc) + cc_ * 8,                     \
           &Bs[buf][p_ * 2048 + w * 512]);                                    \
    }                                                                         \
  } while (0)
  STAGE(0, 0);
  for (int it = 0; it < 16; ++it) {
    int cur = it & 1;
    if (it < 15) {
      STAGE(cur ^ 1, (it + 1) * 64);
      asm volatile("s_waitcnt vmcnt(8)" ::: "memory");
    } else {
      asm volatile("s_waitcnt vmcnt(0)" ::: "memory");
    }
    __builtin_amdgcn_s_barrier();
    __builtin_amdgcn_sched_barrier(0);
#pragma unroll
    for (int ks = 0; ks < 2; ++ks) {
      bf16x8 av[4], bv[4];
#pragma unroll
      for (int m = 0; m < 4; ++m) {
        int r = wr * 64 + m * 16 + ln;
        av[m] = *(const bf16x8*)(const void*)&As[cur][r * 64 + (((ks * 4 + hi) ^ (r & 7)) * 8)];
      }
#pragma unroll
      for (int n = 0; n < 4; ++n) {
        int r = wc * 64 + n * 16 + ln;
        bv[n] = *(const bf16x8*)(const void*)&Bs[cur][r * 64 + (((ks * 4 + hi) ^ (r & 7)) * 8)];
      }
#pragma unroll
      for (int m = 0; m < 4; ++m)
#pragma unroll
        for (int n = 0; n < 4; ++n)
          acc[m][n] = __builtin_amdgcn_mfma_f32_16x16x32_bf16(av[m], bv[n], acc[m][n], 0, 0, 0);
    }
    __builtin_amdgcn_sched_barrier(0);
    __builtin_amdgcn_s_barrier();
  }
#undef STAGE
  float gsv[4];
  float x2v[4][KTOP];
#pragma unroll
  for (int n = 0; n < 4; ++n) {
    int c = C0 + wc * 64 + n * 16 + ln;
    gsv[n] = gamma[c] * Wout[c];
#pragma unroll
    for (int k = 0; k < KTOP; ++k) x2v[n][k] = x2p[((size_t)b * KTOP + k) * HD + c];
  }
#pragma unroll
  for (int m = 0; m < 4; ++m)
#pragma unroll
    for (int j = 0; j < 4; ++j) {
      int row = R0 + wr * 64 + m * 16 + hi * 4 + j;
#pragma unroll
      for (int k = 0; k < KTOP; ++k) {
        float sv = 0.f, s2 = 0.f, sg = 0.f;
#pragma unroll
        for (int n = 0; n < 4; ++n) {
          float v = fast_tanh(acc[m][n][j] + x2v[n][k]);
          sv += v; s2 += v * v; sg += v * gsv[n];
        }
#pragma unroll
        for (int off = 8; off; off >>= 1) {
          sv += __shfl_xor(sv, off);
          s2 += __shfl_xor(s2, off);
          sg += __shfl_xor(sg, off);
        }
        if (ln == 0) {
          float* p = outp + ((size_t)row * KTOP + k) * 3;
          atomicAdd(p, sv);
          atomicAdd(p + 1, s2);
          atomicAdd(p + 2, sg);
        }
      }
    }
}

__global__ void k_end_final(const float* __restrict__ sums,
                            const float* __restrict__ gamma,
                            const float* __restrict__ beta,
                            const float* __restrict__ Wout,
                            const float* __restrict__ beo,
                            const float* __restrict__ mask,
                            float* __restrict__ mel) {
  int bk = blockIdx.x, b = bk / KTOP, k = bk % KTOP;
  int t = threadIdx.x, lane = t & 63, wid = t >> 6;
  __shared__ float red[4][2];
  float pg = 0.f, pb = 0.f;
  for (int i = t; i < HD; i += 256) {
    float wv = Wout[i];
    pg += gamma[i] * wv;
    pb += beta[i] * wv;
  }
#pragma unroll
  for (int off = 32; off; off >>= 1) {
    pg += __shfl_xor(pg, off);
    pb += __shfl_xor(pb, off);
  }
  if (lane == 0) { red[wid][0] = pg; red[wid][1] = pb; }
  __syncthreads();
  float sG = red[0][0] + red[1][0] + red[2][0] + red[3][0];
  float sBW = red[0][1] + red[1][1] + red[2][1] + red[3][1] + beo[0];
  for (int l = t; l < LSEQ; l += 256) {
    int row = b * LSEQ + l;
    const float* s = sums + ((size_t)row * KTOP + k) * 3;
    float sv = s[0], s2 = s[1], sg = s[2];
    float mu = sv * (1.f / (float)HD);
    float var = s2 * (1.f / (float)HD) - mu * mu;
    float rr = rsqrtf(var + 1e-12f);
    float logit = rr * (sg - mu * sG) + sBW;
    float mv = mask[row];
    mel[((size_t)b * KTOP + k) * LSEQ + l] = logit * mv - NEGV * (1.f - mv);
  }
}

// ---------------- host ----------------
extern "C" void kernel_launch(void* const* d_in, const int* in_sizes, int n_in,
                              void* d_out, int out_size, void* d_ws, size_t ws_size,
                              hipStream_t stream) {
  (void)in_sizes; (void)n_in; (void)out_size;
  const float* seq = (const float*)d_in[0];
  const int*   cls = (const int*)d_in[1];
  const float* mask = (const float*)d_in[2];
  const float* Wst = (const float*)d_in[3];
  const float* bst = (const float*)d_in[4];
  const float* Wei = (const float*)d_in[5];
  const float* bei = (const float*)d_in[6];
  const float* gam = (const float*)d_in[7];
  const float* bet = (const float*)d_in[8];
  const float* Weo = (const float*)d_in[9];
  const float* beo = (const float*)d_in[10];
  const float* Wai = (const float*)d_in[11];
  const float* bai = (const float*)d_in[12];
  const float* Wao = (const float*)d_in[13];

  float* out = (float*)d_out;
  float* out0 = out;             // start_predictions  (16,512)
  float* out1 = out0 + 8192;     // end_predictions    (16,5,512)
  float* out2 = out1 + 40960;    // masked_start_logits(16,512)
  float* out3 = out2 + 8192;     // masked_end_logits  (16,5,512)
  float* out4 = out3 + 40960;    // start_top_predictions (16,5)
  float* out5 = out4 + 80;       // end_top_predictions (16,25)
  float* out6 = out5 + 400;      // class_logits (16)

  // ws layout
  char* p = (char*)d_ws;
  unsigned short* seqb = (unsigned short*)p;  p += (size_t)8192 * 1024 * 2;
  unsigned short* w1t  = (unsigned short*)p;  p += (size_t)1024 * 1024 * 2;
  unsigned short* w2t  = (unsigned short*)p;  p += (size_t)1024 * 1024 * 2;
  float* p_ws   = (float*)p;                  p += 8192 * 4;
  int*   idx_ws = (int*)p;                    p += 128 * 4;
  float* x2p    = (float*)p;                  p += (size_t)80 * 1024 * 4;
  float* gw_ws  = (float*)p;                  p += 1024 * 4;
  float* sgb_ws = (float*)p;                  p += 4 * 4;
  float* pa     = (float*)p;                  p += (size_t)16 * 32 * 1024 * 4;
  float* cf     = (float*)p;                  p += (size_t)16 * 1024 * 4;
  float* pans   = (float*)p;                  p += (size_t)16 * 16 * 1024 * 4;
  // tail: X1 (big tier, 16MB) or sums (small tier, 480KB)
  unsigned short* x1 = (unsigned short*)p;
  float* sums = (float*)p;
  size_t base = (size_t)(p - (char*)d_ws);
  size_t need_big = base + (size_t)8192 * 1024 * 2;
  size_t need_small = base + (size_t)8192 * KTOP * 3 * 4;

  k_prep<<<4097, 256, 0, stream>>>(seq, seqb, Wst, bst, mask, out2, Wei, w1t, w2t,
                                   gam, bet, Weo, beo, gw_ws, sgb_ws);

  if (ws_size >= need_big) {
    k_gsm<<<528, 256, 0, stream>>>(seqb, w1t, x1, out2, out0, out4, p_ws, idx_ws);
    k_x2a<<<520, 256, 0, stream>>>(seqb, w2t, idx_ws, bei, x2p,
                                   seq, p_ws, cls, pa, cf);
    k_end2<<<768, 256, 0, stream>>>(x1, x2p, gw_ws, sgb_ws, mask, out3,
                                    pa, cf, Wai, pans);
  } else if (ws_size >= need_small) {
    k_softmax_topk<<<NB, 256, 0, stream>>>(out2, out0, out4, p_ws, idx_ws);
    k_x2init<<<80, 256, 0, stream>>>(bei, x2p);
    k_x2f<<<640, 256, 0, stream>>>(seq, idx_ws, Wei, x2p);
    hipMemsetAsync(sums, 0, (size_t)8192 * KTOP * 3 * sizeof(float), stream);
    k_gemm_end_at<<<dim3(64, 8), 256, 0, stream>>>(seqb, w1t, x2p, gam, Weo, sums);
    k_end_final<<<NB * KTOP, 256, 0, stream>>>(sums, gam, bet, Weo, beo, mask, out3);
    k_ansin_f<<<512, 256, 0, stream>>>(seq, p_ws, cls, pa, cf);
    k_ansmid_f<<<256, 256, 0, stream>>>(pa, cf, Wai, pans);
  }

  k_fin<<<96, 256, 0, stream>>>(out3, out1, out5, pans, bai, Wao, out6);
}

// Round 12
// 85.906 us; speedup vs baseline: 1.0854x; 1.0102x over previous
//
#include <hip/hip_runtime.h>
#include <math.h>

#define HD   1024
#define LSEQ 512
#define NB   16
#define KTOP 5
#define NEGV 1e30f

typedef __bf16 bf16x8 __attribute__((ext_vector_type(8)));
typedef float  f32x4  __attribute__((ext_vector_type(4)));

__device__ inline unsigned short f2bf(float f) {
  unsigned u = __float_as_uint(f);
  unsigned r = (u + 0x7FFFu + ((u >> 16) & 1u)) >> 16;
  return (unsigned short)r;
}
__device__ inline float bf2f(unsigned short u) {
  return __uint_as_float(((unsigned)u) << 16);
}

__device__ inline float fast_tanh(float x) {
  float e = __expf(-2.f * fabsf(x));
  float v = (1.f - e) / (1.f + e);
  return copysignf(v, x);
}

// sum across each 16-lane DPP row via rotate-reduce (VALU pipe, no LDS ops)
__device__ inline float dpp_row_reduce16(float v) {
  int t;
  t = __builtin_amdgcn_update_dpp(0, __float_as_int(v), 0x128, 0xf, 0xf, true);
  v += __int_as_float(t);   // row_ror:8
  t = __builtin_amdgcn_update_dpp(0, __float_as_int(v), 0x124, 0xf, 0xf, true);
  v += __int_as_float(t);   // row_ror:4
  t = __builtin_amdgcn_update_dpp(0, __float_as_int(v), 0x122, 0xf, 0xf, true);
  v += __int_as_float(t);   // row_ror:2
  t = __builtin_amdgcn_update_dpp(0, __float_as_int(v), 0x121, 0xf, 0xf, true);
  v += __int_as_float(t);   // row_ror:1
  return v;
}

#define GLDS(g, l) __builtin_amdgcn_global_load_lds(                      \
    (const __attribute__((address_space(1))) unsigned int*)(g),          \
    (__attribute__((address_space(3))) unsigned int*)(l), 16, 0, 0)

// =============== device bodies ===============

// ---- row log_softmax + top5 over 512 (256 threads) ----
__device__ __forceinline__ void sm_body(int row, const float* __restrict__ xin,
                                        float* __restrict__ lsm_out,
                                        float* __restrict__ top_out,
                                        float* __restrict__ p_out,
                                        int* __restrict__ idx_out) {
  __shared__ float redf[4];
  __shared__ int redi[4];
  __shared__ float bc_m, bc_s;
  __shared__ int bc_i;
  int t = threadIdx.x, lane = t & 63, wid = t >> 6;
  const float* x = xin + (size_t)row * LSEQ;
  float x0 = x[t], x1 = x[t + 256];

  float m = fmaxf(x0, x1);
#pragma unroll
  for (int off = 32; off; off >>= 1) m = fmaxf(m, __shfl_xor(m, off));
  if (lane == 0) redf[wid] = m;
  __syncthreads();
  if (t == 0) bc_m = fmaxf(fmaxf(redf[0], redf[1]), fmaxf(redf[2], redf[3]));
  __syncthreads();
  m = bc_m;

  float e0 = expf(x0 - m), e1 = expf(x1 - m);
  float s = e0 + e1;
#pragma unroll
  for (int off = 32; off; off >>= 1) s += __shfl_xor(s, off);
  if (lane == 0) redf[wid] = s;
  __syncthreads();
  if (t == 0) bc_s = redf[0] + redf[1] + redf[2] + redf[3];
  __syncthreads();
  s = bc_s;
  float ls = logf(s);

  lsm_out[(size_t)row * LSEQ + t] = x0 - m - ls;
  lsm_out[(size_t)row * LSEQ + t + 256] = x1 - m - ls;
  if (p_out) {
    float inv = 1.f / s;
    p_out[(size_t)row * LSEQ + t] = e0 * inv;
    p_out[(size_t)row * LSEQ + t + 256] = e1 * inv;
  }

  bool a0 = true, a1 = true;
  for (int it = 0; it < KTOP; ++it) {
    float v0 = a0 ? x0 : -INFINITY;
    float v1 = a1 ? x1 : -INFINITY;
    float bv = v0; int bi = t;
    if (v1 > bv) { bv = v1; bi = t + 256; }
#pragma unroll
    for (int off = 32; off; off >>= 1) {
      float ov = __shfl_xor(bv, off);
      int oi = __shfl_xor(bi, off);
      if (ov > bv || (ov == bv && oi < bi)) { bv = ov; bi = oi; }
    }
    __syncthreads();
    if (lane == 0) { redf[wid] = bv; redi[wid] = bi; }
    __syncthreads();
    if (t == 0) {
      float wv = redf[0]; int wi = redi[0];
      for (int w = 1; w < 4; ++w)
        if (redf[w] > wv || (redf[w] == wv && redi[w] < wi)) { wv = redf[w]; wi = redi[w]; }
      top_out[row * KTOP + it] = wv - m - ls;
      if (idx_out) idx_out[row * KTOP + it] = wi;
      bc_i = wi;
    }
    __syncthreads();
    int wi = bc_i;
    if (wi == t) a0 = false;
    if (wi == t + 256) a1 = false;
  }
}

// ---- 128x128 MFMA GEMM tile, single-buffered BK=64 (32KB LDS, m97 pattern) ----
__device__ __forceinline__ void gemm_body(int R0, int C0,
                                          const unsigned short* __restrict__ Abf,
                                          const unsigned short* __restrict__ Bt,
                                          unsigned short* __restrict__ X1) {
  __shared__ unsigned short SH[16384];  // As[8192] | Bs[8192]  (32KB)
  unsigned short* As = SH;
  unsigned short* Bs = SH + 8192;
  int t = threadIdx.x;
  int w = t >> 6, lane = t & 63, ln = lane & 15, hi = lane >> 4;
  int wr = w >> 1, wc = w & 1;

  f32x4 acc[4][4] = {};

#define STAGE(kc)                                                             \
  do {                                                                        \
    _Pragma("unroll")                                                         \
    for (int p_ = 0; p_ < 4; ++p_) {                                          \
      int rr_ = p_ * 32 + (t >> 3);                                           \
      int cc_ = (t & 7) ^ (rr_ & 7);                                          \
      GLDS(Abf + (size_t)(R0 + rr_) * HD + (kc) + cc_ * 8,                    \
           As + p_ * 2048 + w * 512);                                         \
      GLDS(Bt + (size_t)(C0 + rr_) * HD + (kc) + cc_ * 8,                     \
           Bs + p_ * 2048 + w * 512);                                         \
    }                                                                         \
  } while (0)

  for (int it = 0; it < 16; ++it) {
    if (it) __syncthreads();               // all waves done reading LDS
    STAGE(it * 64);
    asm volatile("s_waitcnt vmcnt(0)" ::: "memory");
    __builtin_amdgcn_s_barrier();
#pragma unroll
    for (int ks = 0; ks < 2; ++ks) {
      bf16x8 av[4], bv[4];
#pragma unroll
      for (int m = 0; m < 4; ++m) {
        int r = wr * 64 + m * 16 + ln;
        av[m] = *(const bf16x8*)(const void*)&As[r * 64 + (((ks * 4 + hi) ^ (r & 7)) * 8)];
      }
#pragma unroll
      for (int n = 0; n < 4; ++n) {
        int r = wc * 64 + n * 16 + ln;
        bv[n] = *(const bf16x8*)(const void*)&Bs[r * 64 + (((ks * 4 + hi) ^ (r & 7)) * 8)];
      }
#pragma unroll
      for (int m = 0; m < 4; ++m)
#pragma unroll
        for (int n = 0; n < 4; ++n)
          acc[m][n] = __builtin_amdgcn_mfma_f32_16x16x32_bf16(av[m], bv[n], acc[m][n], 0, 0, 0);
    }
  }
#undef STAGE

#pragma unroll
  for (int m = 0; m < 4; ++m)
#pragma unroll
    for (int j = 0; j < 4; ++j) {
      int row = R0 + wr * 64 + m * 16 + hi * 4 + j;
#pragma unroll
      for (int n = 0; n < 4; ++n) {
        int col = C0 + wc * 64 + n * 16 + ln;
        X1[(size_t)row * HD + col] = f2bf(acc[m][n][j]);
      }
    }
}

// ---- X2 MFMA gather-GEMM, single-buffered ----
__device__ __forceinline__ void x2gemm_body(int cid,
                                            const unsigned short* __restrict__ seqb,
                                            const unsigned short* __restrict__ w2t,
                                            const int* __restrict__ idx,
                                            const float* __restrict__ bei,
                                            float* __restrict__ x2p) {
  __shared__ unsigned short SH2[16384];
  unsigned short* As = SH2;
  unsigned short* Bs = SH2 + 8192;
  int t = threadIdx.x;
  int w = t >> 6, lane = t & 63, ln = lane & 15, hi = lane >> 4;
  int wr = w >> 1, wc = w & 1;
  int C0 = cid * 128;

  size_t abase[4];
#pragma unroll
  for (int p_ = 0; p_ < 4; ++p_) {
    int rr = p_ * 32 + (t >> 3);
    int bk = rr < 80 ? rr : 0;
    int l = idx[bk];
    abase[p_] = ((size_t)((bk / KTOP) * LSEQ + l)) * HD;
  }

  f32x4 acc[4][4] = {};

#define STAGE2(kc)                                                            \
  do {                                                                        \
    _Pragma("unroll")                                                         \
    for (int p_ = 0; p_ < 4; ++p_) {                                          \
      int rr_ = p_ * 32 + (t >> 3);                                           \
      int cc_ = (t & 7) ^ (rr_ & 7);                                          \
      GLDS(seqb + abase[p_] + (kc) + cc_ * 8,                                 \
           As + p_ * 2048 + w * 512);                                         \
      GLDS(w2t + (size_t)(C0 + rr_) * HD + (kc) + cc_ * 8,                    \
           Bs + p_ * 2048 + w * 512);                                         \
    }                                                                         \
  } while (0)

  for (int it = 0; it < 16; ++it) {
    if (it) __syncthreads();
    STAGE2(it * 64);
    asm volatile("s_waitcnt vmcnt(0)" ::: "memory");
    __builtin_amdgcn_s_barrier();
#pragma unroll
    for (int ks = 0; ks < 2; ++ks) {
      bf16x8 av[4], bv[4];
#pragma unroll
      for (int m = 0; m < 4; ++m) {
        int r = wr * 64 + m * 16 + ln;
        av[m] = *(const bf16x8*)(const void*)&As[r * 64 + (((ks * 4 + hi) ^ (r & 7)) * 8)];
      }
#pragma unroll
      for (int n = 0; n < 4; ++n) {
        int r = wc * 64 + n * 16 + ln;
        bv[n] = *(const bf16x8*)(const void*)&Bs[r * 64 + (((ks * 4 + hi) ^ (r & 7)) * 8)];
      }
#pragma unroll
      for (int m = 0; m < 4; ++m)
#pragma unroll
        for (int n = 0; n < 4; ++n)
          acc[m][n] = __builtin_amdgcn_mfma_f32_16x16x32_bf16(av[m], bv[n], acc[m][n], 0, 0, 0);
    }
  }
#undef STAGE2

#pragma unroll
  for (int m = 0; m < 4; ++m)
#pragma unroll
    for (int j = 0; j < 4; ++j) {
      int row = wr * 64 + m * 16 + hi * 4 + j;
      if (row < 80) {
#pragma unroll
        for (int n = 0; n < 4; ++n) {
          int col = C0 + wc * 64 + n * 16 + ln;
          x2p[(size_t)row * HD + col] = acc[m][n][j] + bei[col];
        }
      }
    }
}

// ---- answer-feature partial (p_ws weights, bf16 seq stream: halves HBM traffic) ----
__device__ __forceinline__ void ansin_body(int q,
                                           const unsigned short* __restrict__ seqb,
                                           const float* __restrict__ seq,
                                           const float* __restrict__ p_ws,
                                           const int* __restrict__ cls,
                                           float* __restrict__ pa,
                                           float* __restrict__ cf) {
  __shared__ float ps[16];
  int b = q >> 5, s = q & 31, t = threadIdx.x;
  if (t < 16) ps[t] = p_ws[b * LSEQ + s * 16 + t];
  __syncthreads();
  const unsigned short* sb = seqb + (size_t)(b * LSEQ + s * 16) * HD;
  float4 acc = make_float4(0.f, 0.f, 0.f, 0.f);
#pragma unroll
  for (int r = 0; r < 16; ++r) {
    ushort4 u = *(const ushort4*)(sb + (size_t)r * HD + 4 * t);
    float p = ps[r];
    acc.x = fmaf(p, bf2f(u.x), acc.x);
    acc.y = fmaf(p, bf2f(u.y), acc.y);
    acc.z = fmaf(p, bf2f(u.z), acc.z);
    acc.w = fmaf(p, bf2f(u.w), acc.w);
  }
  *(float4*)(pa + ((size_t)b * 32 + s) * HD + 4 * t) = acc;
  if (s == 0) {
    int ci = cls[b];
    *(float4*)(cf + (size_t)b * HD + 4 * t) =
        *(const float4*)(seq + (size_t)(b * LSEQ + ci) * HD + 4 * t);  // class feat stays f32-exact
  }
}

// ---- per-row tanh+LN+logit: 16 rows/block, 16-lane group per row, DPP reduce ----
__device__ __forceinline__ void endrow_body(int bx, const unsigned short* __restrict__ X1,
                                            const float* __restrict__ x2p,
                                            const float* __restrict__ gw_ws,
                                            const float* __restrict__ sgb_ws,
                                            const float* __restrict__ mask,
                                            float* __restrict__ mel) {
  __shared__ float x2e[KTOP * HD];  // 20KB: exp2(A*x2)
  const float A = 2.885390081777927f;  // 2*log2(e)
  int t = threadIdx.x, wave = t >> 6, lane = t & 63;
  int g = lane >> 4, l16 = lane & 15;
  int row = bx * 16 + wave * 4 + g;
  int b = row >> 9, l = row & 511;

  {
    const float* src = x2p + (size_t)b * KTOP * HD;
    for (int i = t; i < KTOP * HD; i += 256)
      x2e[i] = __builtin_amdgcn_exp2f(src[i] * A);
  }
  float mv = mask[row];
  float sG = sgb_ws[0], sBW = sgb_ws[1];
  __syncthreads();

  if (mv == 0.f) {  // masked row: logit irrelevant, output is exactly -NEGV
    if (l16 == 0) {
#pragma unroll
      for (int k = 0; k < KTOP; ++k)
        mel[((size_t)b * KTOP + k) * LSEQ + l] = -NEGV;
    }
    return;
  }

  float av[KTOP] = {}, a2[KTOP] = {}, ag[KTOP] = {};
  const unsigned short* xrow = X1 + (size_t)row * HD;
#pragma unroll 4
  for (int j = 0; j < 16; ++j) {
    int col = j * 64 + l16 * 4;       // 16 lanes cover 128B contiguous per row
    ushort4 u = *(const ushort4*)(xrow + col);
    float4 gwv = *(const float4*)(gw_ws + col);
    float e0 = __builtin_amdgcn_exp2f(bf2f(u.x) * A);
    float e1 = __builtin_amdgcn_exp2f(bf2f(u.y) * A);
    float e2 = __builtin_amdgcn_exp2f(bf2f(u.z) * A);
    float e3 = __builtin_amdgcn_exp2f(bf2f(u.w) * A);
#pragma unroll
    for (int k = 0; k < KTOP; ++k) {
      float4 xq = *(const float4*)&x2e[k * HD + col];
      float v0 = fmaf(-2.f, __builtin_amdgcn_rcpf(fmaf(e0, xq.x, 1.f)), 1.f);
      float v1 = fmaf(-2.f, __builtin_amdgcn_rcpf(fmaf(e1, xq.y, 1.f)), 1.f);
      float v2 = fmaf(-2.f, __builtin_amdgcn_rcpf(fmaf(e2, xq.z, 1.f)), 1.f);
      float v3 = fmaf(-2.f, __builtin_amdgcn_rcpf(fmaf(e3, xq.w, 1.f)), 1.f);
      av[k] += v0 + v1 + v2 + v3;
      a2[k] = fmaf(v0, v0, a2[k]); a2[k] = fmaf(v1, v1, a2[k]);
      a2[k] = fmaf(v2, v2, a2[k]); a2[k] = fmaf(v3, v3, a2[k]);
      ag[k] = fmaf(v0, gwv.x, ag[k]); ag[k] = fmaf(v1, gwv.y, ag[k]);
      ag[k] = fmaf(v2, gwv.z, ag[k]); ag[k] = fmaf(v3, gwv.w, ag[k]);
    }
  }
#pragma unroll
  for (int k = 0; k < KTOP; ++k) {
    float sv = dpp_row_reduce16(av[k]);
    float s2 = dpp_row_reduce16(a2[k]);
    float sg = dpp_row_reduce16(ag[k]);
    if (l16 == 0) {
      float mu = sv * (1.f / (float)HD);
      float var = s2 * (1.f / (float)HD) - mu * mu;
      float rr = rsqrtf(var + 1e-12f);
      float logit = rr * (sg - mu * sG) + sBW;
      mel[((size_t)b * KTOP + k) * LSEQ + l] = logit * mv - NEGV * (1.f - mv);
    }
  }
}

// ---- answer mid GEMM slice ----
__device__ __forceinline__ void ansmid_body(int q, const float* __restrict__ pa,
                                            const float* __restrict__ cf,
                                            const float* __restrict__ Wai,
                                            float* __restrict__ pans) {
  __shared__ float a_s[128];
  int b = q >> 4, c = q & 15, t = threadIdx.x;
  if (t < 128) {
    int i = c * 128 + t;
    float av;
    if (i < HD) {
      av = 0.f;
#pragma unroll
      for (int s = 0; s < 32; ++s) av += pa[((size_t)b * 32 + s) * HD + i];
    } else {
      av = cf[(size_t)b * HD + (i - HD)];
    }
    a_s[t] = av;
  }
  __syncthreads();
  float4 acc = make_float4(0.f, 0.f, 0.f, 0.f);
#pragma unroll 8
  for (int r = 0; r < 128; ++r) {
    float4 wv = *(const float4*)(Wai + (size_t)(c * 128 + r) * HD + 4 * t);
    float a = a_s[r];
    acc.x = fmaf(a, wv.x, acc.x);
    acc.y = fmaf(a, wv.y, acc.y);
    acc.z = fmaf(a, wv.z, acc.z);
    acc.w = fmaf(a, wv.w, acc.w);
  }
  *(float4*)(pans + ((size_t)b * 16 + c) * HD + 4 * t) = acc;
}

__device__ __forceinline__ void ansfinal_body(int b, const float* __restrict__ pans,
                                              const float* __restrict__ bai,
                                              const float* __restrict__ Wao,
                                              float* __restrict__ out6) {
  __shared__ float red[4];
  int t = threadIdx.x, lane = t & 63, wid = t >> 6;
  float4 a = *(const float4*)(bai + 4 * t);
#pragma unroll
  for (int c = 0; c < 16; ++c) {
    float4 p = *(const float4*)(pans + ((size_t)b * 16 + c) * HD + 4 * t);
    a.x += p.x; a.y += p.y; a.z += p.z; a.w += p.w;
  }
  float4 wo = *(const float4*)(Wao + 4 * t);
  float part = fast_tanh(a.x) * wo.x + fast_tanh(a.y) * wo.y +
               fast_tanh(a.z) * wo.z + fast_tanh(a.w) * wo.w;
#pragma unroll
  for (int off = 32; off; off >>= 1) part += __shfl_xor(part, off);
  if (lane == 0) red[wid] = part;
  __syncthreads();
  if (t == 0) out6[b] = red[0] + red[1] + red[2] + red[3];
}

// =============== kernels ===============

// K1: conv+start (2048) | W1/W2 transpose (2048) | LN consts (1)
__global__ void k_prep(const float* __restrict__ seq,
                       unsigned short* __restrict__ seqb,
                       const float* __restrict__ Wst,
                       const float* __restrict__ bst,
                       const float* __restrict__ mask,
                       float* __restrict__ msl,
                       const float* __restrict__ Wei,
                       unsigned short* __restrict__ w1t,
                       unsigned short* __restrict__ w2t,
                       const float* __restrict__ gam,
                       const float* __restrict__ bet,
                       const float* __restrict__ Weo,
                       const float* __restrict__ beo,
                       float* __restrict__ gw_ws,
                       float* __restrict__ sgb_ws) {
  __shared__ unsigned short tile[32][33];
  __shared__ float redp[4][2];
  int bx = blockIdx.x;
  if (bx < 2048) {
    int wave = threadIdx.x >> 6, lane = threadIdx.x & 63;
    int row = bx * 4 + wave;
    const float4* s4 = (const float4*)(seq + (size_t)row * HD);
    const float4* w4 = (const float4*)Wst;
    ushort4* o4 = (ushort4*)(seqb + (size_t)row * HD);
    float acc = 0.f;
#pragma unroll
    for (int m = 0; m < 4; ++m) {
      int i = lane + 64 * m;
      float4 a = s4[i], w = w4[i];
      acc += a.x * w.x + a.y * w.y + a.z * w.z + a.w * w.w;
      ushort4 o;
      o.x = f2bf(a.x); o.y = f2bf(a.y); o.z = f2bf(a.z); o.w = f2bf(a.w);
      o4[i] = o;
    }
#pragma unroll
    for (int off = 32; off; off >>= 1) acc += __shfl_xor(acc, off);
    if (lane == 0) {
      float logit = acc + bst[0];
      float mv = mask[row];
      msl[row] = logit * mv - NEGV * (1.f - mv);
    }
  } else if (bx < 4096) {
    int tb = bx - 2048;
    const float* Wsrc = Wei + (tb >= 1024 ? (size_t)HD * HD : 0);
    unsigned short* Wdst = (tb >= 1024) ? w2t : w1t;
    int tb2 = tb & 1023;
    int h0 = (tb2 & 31) * 32, d0 = (tb2 >> 5) * 32;
    int tx = threadIdx.x & 31, ty = threadIdx.x >> 5;
#pragma unroll
    for (int i = 0; i < 4; ++i)
      tile[ty + 8 * i][tx] = f2bf(Wsrc[(size_t)(h0 + ty + 8 * i) * HD + d0 + tx]);
    __syncthreads();
#pragma unroll
    for (int i = 0; i < 4; ++i)
      Wdst[(size_t)(d0 + ty + 8 * i) * HD + h0 + tx] = tile[tx][ty + 8 * i];
  } else {
    int t = threadIdx.x, wave = t >> 6, lane = t & 63;
    float4 g = ((const float4*)gam)[t];
    float4 w = ((const float4*)Weo)[t];
    float4 bv = ((const float4*)bet)[t];
    float4 gwv = make_float4(g.x * w.x, g.y * w.y, g.z * w.z, g.w * w.w);
    ((float4*)gw_ws)[t] = gwv;
    float pg = gwv.x + gwv.y + gwv.z + gwv.w;
    float pb = bv.x * w.x + bv.y * w.y + bv.z * w.z + bv.w * w.w;
#pragma unroll
    for (int off = 32; off; off >>= 1) {
      pg += __shfl_xor(pg, off);
      pb += __shfl_xor(pb, off);
    }
    if (lane == 0) { redp[wave][0] = pg; redp[wave][1] = pb; }
    __syncthreads();
    if (t == 0) {
      sgb_ws[0] = redp[0][0] + redp[1][0] + redp[2][0] + redp[3][0];
      sgb_ws[1] = redp[0][1] + redp[1][1] + redp[2][1] + redp[3][1] + beo[0];
    }
  }
}

__global__ void k_softmax_topk(const float* __restrict__ xin,
                               float* __restrict__ lsm_out,
                               float* __restrict__ top_out,
                               float* __restrict__ p_out,
                               int* __restrict__ idx_out) {
  sm_body(blockIdx.x, xin, lsm_out, top_out, p_out, idx_out);
}

// K2: sm1 (ids 0..15) + XCD-affine gemm (ids 16..527)
__launch_bounds__(256, 4)
__global__ void k_gsm(const unsigned short* __restrict__ Abf,
                      const unsigned short* __restrict__ Bt,
                      unsigned short* __restrict__ X1,
                      const float* __restrict__ msl,
                      float* __restrict__ lsm_out,
                      float* __restrict__ top_out,
                      float* __restrict__ p_out,
                      int* __restrict__ idx_out) {
  int id = blockIdx.x;
  if (id < 16) {
    sm_body(id, msl, lsm_out, top_out, p_out, idx_out);
  } else {
    int gid = id - 16;  // gid%8 == id%8 -> row-panel XCD affinity
    gemm_body((gid & 63) * 128, (gid >> 6) * 128, Abf, Bt, X1);
  }
}

// K3: x2 MFMA gather-gemm (ids 0..7) + ans_in (ids 8..519, bf16 stream)
__launch_bounds__(256, 4)
__global__ void k_x2a(const unsigned short* __restrict__ seqb,
                      const unsigned short* __restrict__ w2t,
                      const int* __restrict__ idx,
                      const float* __restrict__ bei,
                      float* __restrict__ x2p,
                      const float* __restrict__ seq,
                      const float* __restrict__ p_ws,
                      const int* __restrict__ cls,
                      float* __restrict__ pa,
                      float* __restrict__ cf) {
  int id = blockIdx.x;
  if (id < 8) x2gemm_body(id, seqb, w2t, idx, bei, x2p);
  else ansin_body(id - 8, seqb, seq, p_ws, cls, pa, cf);
}

// K4: endrow (512, 16 rows each) + ans_mid (256)
__global__ void k_end2(const unsigned short* __restrict__ X1,
                       const float* __restrict__ x2p,
                       const float* __restrict__ gw_ws,
                       const float* __restrict__ sgb_ws,
                       const float* __restrict__ mask,
                       float* __restrict__ mel,
                       const float* __restrict__ pa,
                       const float* __restrict__ cf,
                       const float* __restrict__ Wai,
                       float* __restrict__ pans) {
  int bx = blockIdx.x;
  if (bx < 512) endrow_body(bx, X1, x2p, gw_ws, sgb_ws, mask, mel);
  else ansmid_body(bx - 512, pa, cf, Wai, pans);
}

// K5: softmax2 (80) + ans_final (16)
__global__ void k_fin(const float* __restrict__ mel,
                      float* __restrict__ lsm_out,
                      float* __restrict__ top_out,
                      const float* __restrict__ pans,
                      const float* __restrict__ bai,
                      const float* __restrict__ Wao,
                      float* __restrict__ out6) {
  int bx = blockIdx.x;
  if (bx < NB * KTOP) sm_body(bx, mel, lsm_out, top_out, nullptr, nullptr);
  else ansfinal_body(bx - NB * KTOP, pans, bai, Wao, out6);
}

// =============== fallback-tier kernels (small ws) ===============
__global__ void k_x2init(const float* __restrict__ bei, float* __restrict__ x2p) {
  ((float4*)(x2p + (size_t)blockIdx.x * HD))[threadIdx.x] = ((const float4*)bei)[threadIdx.x];
}

__global__ void k_x2f(const float* __restrict__ seq, const int* __restrict__ idx,
                      const float* __restrict__ Wei, float* __restrict__ x2p) {
  __shared__ float srow[128];
  int q = blockIdx.x;
  int bk = q >> 3, s = q & 7, t = threadIdx.x;
  int b = bk / KTOP;
  int l = idx[bk];
  if (t < 128) srow[t] = seq[((size_t)(b * LSEQ + l)) * HD + s * 128 + t];
  __syncthreads();
  const float* W2 = Wei + (size_t)HD * HD + (size_t)s * 128 * HD;
  float4 acc = make_float4(0.f, 0.f, 0.f, 0.f);
#pragma unroll 8
  for (int h = 0; h < 128; ++h) {
    float4 wv = *(const float4*)(W2 + (size_t)h * HD + 4 * t);
    float sv = srow[h];
    acc.x = fmaf(sv, wv.x, acc.x);
    acc.y = fmaf(sv, wv.y, acc.y);
    acc.z = fmaf(sv, wv.z, acc.z);
    acc.w = fmaf(sv, wv.w, acc.w);
  }
  float* dst = x2p + (size_t)bk * HD + 4 * t;
  atomicAdd(dst + 0, acc.x);
  atomicAdd(dst + 1, acc.y);
  atomicAdd(dst + 2, acc.z);
  atomicAdd(dst + 3, acc.w);
}

__global__ void k_ansin_f(const unsigned short* __restrict__ seqb,
                          const float* __restrict__ seq, const float* __restrict__ p_ws,
                          const int* __restrict__ cls, float* __restrict__ pa,
                          float* __restrict__ cf) {
  ansin_body(blockIdx.x, seqb, seq, p_ws, cls, pa, cf);
}
__global__ void k_ansmid_f(const float* __restrict__ pa, const float* __restrict__ cf,
                           const float* __restrict__ Wai, float* __restrict__ pans) {
  ansmid_body(blockIdx.x, pa, cf, Wai, pans);
}

__launch_bounds__(256, 2)
__global__ void k_gemm_end_at(const unsigned short* __restrict__ Abf,
                              const unsigned short* __restrict__ Bt,
                              const float* __restrict__ x2p,
                              const float* __restrict__ gamma,
                              const float* __restrict__ Wout,
                              float* __restrict__ outp) {
  __shared__ unsigned short As[2][128 * 64];
  __shared__ unsigned short Bs[2][128 * 64];
  int t = threadIdx.x;
  int w = t >> 6, lane = t & 63, ln = lane & 15, hi = lane >> 4;
  int wr = w >> 1, wc = w & 1;
  int R0 = blockIdx.x * 128, C0 = blockIdx.y * 128;
  int b = R0 >> 9;
  f32x4 acc[4][4] = {};
#define STAGE(buf, kc)                                                        \
  do {                                                                        \
    _Pragma("unroll")                                                         \
    for (int p_ = 0; p_ < 4; ++p_) {                                          \
      int rr_ = p_ * 32 + (t >> 3);                                           \
      int cc_ = (t & 7) ^ (rr_ & 7);                                          \
      GLDS(Abf + (size_t)(R0 + rr_) * HD + (kc) + cc_ * 8,                    \
           &As[buf][p_ * 2048 + w * 512]);                                    \
      GLDS(Bt + (size_t)(C0 + rr_) * HD + (kc) + cc_ * 8,                     \
           &Bs[buf][p_ * 2048 + w * 512]);                                    \
    }                                                                         \
  } while (0)
  STAGE(0, 0);
  for (int it = 0; it < 16; ++it) {
    int cur = it & 1;
    if (it < 15) {
      STAGE(cur ^ 1, (it + 1) * 64);
      asm volatile("s_waitcnt vmcnt(8)" ::: "memory");
    } else {
      asm volatile("s_waitcnt vmcnt(0)" ::: "memory");
    }
    __builtin_amdgcn_s_barrier();
    __builtin_amdgcn_sched_barrier(0);
#pragma unroll
    for (int ks = 0; ks < 2; ++ks) {
      bf16x8 av[4], bv[4];
#pragma unroll
      for (int m = 0; m < 4; ++m) {
        int r = wr * 64 + m * 16 + ln;
        av[m] = *(const bf16x8*)(const void*)&As[cur][r * 64 + (((ks * 4 + hi) ^ (r & 7)) * 8)];
      }
#pragma unroll
      for (int n = 0; n < 4; ++n) {
        int r = wc * 64 + n * 16 + ln;
        bv[n] = *(const bf16x8*)(const void*)&Bs[cur][r * 64 + (((ks * 4 + hi) ^ (r & 7)) * 8)];
      }
#pragma unroll
      for (int m = 0; m < 4; ++m)
#pragma unroll
        for (int n = 0; n < 4; ++n)
          acc[m][n] = __builtin_amdgcn_mfma_f32_16x16x32_bf16(av[m], bv[n], acc[m][n], 0, 0, 0);
    }
    __builtin_amdgcn_sched_barrier(0);
    __builtin_amdgcn_s_barrier();
  }
#undef STAGE
  float gsv[4];
  float x2v[4][KTOP];
#pragma unroll
  for (int n = 0; n < 4; ++n) {
    int c = C0 + wc * 64 + n * 16 + ln;
    gsv[n] = gamma[c] * Wout[c];
#pragma unroll
    for (int k = 0; k < KTOP; ++k) x2v[n][k] = x2p[((size_t)b * KTOP + k) * HD + c];
  }
#pragma unroll
  for (int m = 0; m < 4; ++m)
#pragma unroll
    for (int j = 0; j < 4; ++j) {
      int row = R0 + wr * 64 + m * 16 + hi * 4 + j;
#pragma unroll
      for (int k = 0; k < KTOP; ++k) {
        float sv = 0.f, s2 = 0.f, sg = 0.f;
#pragma unroll
        for (int n = 0; n < 4; ++n) {
          float v = fast_tanh(acc[m][n][j] + x2v[n][k]);
          sv += v; s2 += v * v; sg += v * gsv[n];
        }
#pragma unroll
        for (int off = 8; off; off >>= 1) {
          sv += __shfl_xor(sv, off);
          s2 += __shfl_xor(s2, off);
          sg += __shfl_xor(sg, off);
        }
        if (ln == 0) {
          float* p = outp + ((size_t)row * KTOP + k) * 3;
          atomicAdd(p, sv);
          atomicAdd(p + 1, s2);
          atomicAdd(p + 2, sg);
        }
      }
    }
}

__global__ void k_end_final(const float* __restrict__ sums,
                            const float* __restrict__ gamma,
                            const float* __restrict__ beta,
                            const float* __restrict__ Wout,
                            const float* __restrict__ beo,
                            const float* __restrict__ mask,
                            float* __restrict__ mel) {
  int bk = blockIdx.x, b = bk / KTOP, k = bk % KTOP;
  int t = threadIdx.x, lane = t & 63, wid = t >> 6;
  __shared__ float red[4][2];
  float pg = 0.f, pb = 0.f;
  for (int i = t; i < HD; i += 256) {
    float wv = Wout[i];
    pg += gamma[i] * wv;
    pb += beta[i] * wv;
  }
#pragma unroll
  for (int off = 32; off; off >>= 1) {
    pg += __shfl_xor(pg, off);
    pb += __shfl_xor(pb, off);
  }
  if (lane == 0) { red[wid][0] = pg; red[wid][1] = pb; }
  __syncthreads();
  float sG = red[0][0] + red[1][0] + red[2][0] + red[3][0];
  float sBW = red[0][1] + red[1][1] + red[2][1] + red[3][1] + beo[0];
  for (int l = t; l < LSEQ; l += 256) {
    int row = b * LSEQ + l;
    const float* s = sums + ((size_t)row * KTOP + k) * 3;
    float sv = s[0], s2 = s[1], sg = s[2];
    float mu = sv * (1.f / (float)HD);
    float var = s2 * (1.f / (float)HD) - mu * mu;
    float rr = rsqrtf(var + 1e-12f);
    float logit = rr * (sg - mu * sG) + sBW;
    float mv = mask[row];
    mel[((size_t)b * KTOP + k) * LSEQ + l] = logit * mv - NEGV * (1.f - mv);
  }
}

// ---------------- host ----------------
extern "C" void kernel_launch(void* const* d_in, const int* in_sizes, int n_in,
                              void* d_out, int out_size, void* d_ws, size_t ws_size,
                              hipStream_t stream) {
  (void)in_sizes; (void)n_in; (void)out_size;
  const float* seq = (const float*)d_in[0];
  const int*   cls = (const int*)d_in[1];
  const float* mask = (const float*)d_in[2];
  const float* Wst = (const float*)d_in[3];
  const float* bst = (const float*)d_in[4];
  const float* Wei = (const float*)d_in[5];
  const float* bei = (const float*)d_in[6];
  const float* gam = (const float*)d_in[7];
  const float* bet = (const float*)d_in[8];
  const float* Weo = (const float*)d_in[9];
  const float* beo = (const float*)d_in[10];
  const float* Wai = (const float*)d_in[11];
  const float* bai = (const float*)d_in[12];
  const float* Wao = (const float*)d_in[13];

  float* out = (float*)d_out;
  float* out0 = out;             // start_predictions  (16,512)
  float* out1 = out0 + 8192;     // end_predictions    (16,5,512)
  float* out2 = out1 + 40960;    // masked_start_logits(16,512)
  float* out3 = out2 + 8192;     // masked_end_logits  (16,5,512)
  float* out4 = out3 + 40960;    // start_top_predictions (16,5)
  float* out5 = out4 + 80;       // end_top_predictions (16,25)
  float* out6 = out5 + 400;      // class_logits (16)

  // ws layout
  char* p = (char*)d_ws;
  unsigned short* seqb = (unsigned short*)p;  p += (size_t)8192 * 1024 * 2;
  unsigned short* w1t  = (unsigned short*)p;  p += (size_t)1024 * 1024 * 2;
  unsigned short* w2t  = (unsigned short*)p;  p += (size_t)1024 * 1024 * 2;
  float* p_ws   = (float*)p;                  p += 8192 * 4;
  int*   idx_ws = (int*)p;                    p += 128 * 4;
  float* x2p    = (float*)p;                  p += (size_t)80 * 1024 * 4;
  float* gw_ws  = (float*)p;                  p += 1024 * 4;
  float* sgb_ws = (float*)p;                  p += 4 * 4;
  float* pa     = (float*)p;                  p += (size_t)16 * 32 * 1024 * 4;
  float* cf     = (float*)p;                  p += (size_t)16 * 1024 * 4;
  float* pans   = (float*)p;                  p += (size_t)16 * 16 * 1024 * 4;
  // tail: X1 (big tier, 16MB) or sums (small tier, 480KB)
  unsigned short* x1 = (unsigned short*)p;
  float* sums = (float*)p;
  size_t base = (size_t)(p - (char*)d_ws);
  size_t need_big = base + (size_t)8192 * 1024 * 2;
  size_t need_small = base + (size_t)8192 * KTOP * 3 * 4;

  k_prep<<<4097, 256, 0, stream>>>(seq, seqb, Wst, bst, mask, out2, Wei, w1t, w2t,
                                   gam, bet, Weo, beo, gw_ws, sgb_ws);

  if (ws_size >= need_big) {
    k_gsm<<<528, 256, 0, stream>>>(seqb, w1t, x1, out2, out0, out4, p_ws, idx_ws);
    k_x2a<<<520, 256, 0, stream>>>(seqb, w2t, idx_ws, bei, x2p,
                                   seq, p_ws, cls, pa, cf);
    k_end2<<<768, 256, 0, stream>>>(x1, x2p, gw_ws, sgb_ws, mask, out3,
                                    pa, cf, Wai, pans);
  } else if (ws_size >= need_small) {
    k_softmax_topk<<<NB, 256, 0, stream>>>(out2, out0, out4, p_ws, idx_ws);
    k_x2init<<<80, 256, 0, stream>>>(bei, x2p);
    k_x2f<<<640, 256, 0, stream>>>(seq, idx_ws, Wei, x2p);
    hipMemsetAsync(sums, 0, (size_t)8192 * KTOP * 3 * sizeof(float), stream);
    k_gemm_end_at<<<dim3(64, 8), 256, 0, stream>>>(seqb, w1t, x2p, gam, Weo, sums);
    k_end_final<<<NB * KTOP, 256, 0, stream>>>(sums, gam, bet, Weo, beo, mask, out3);
    k_ansin_f<<<512, 256, 0, stream>>>(seqb, seq, p_ws, cls, pa, cf);
    k_ansmid_f<<<256, 256, 0, stream>>>(pa, cf, Wai, pans);
  }

  k_fin<<<96, 256, 0, stream>>>(out3, out1, out5, pans, bai, Wao, out6);
}